// Round 7
// baseline (733.646 us; speedup 1.0000x reference)
//
#include <hip/hip_runtime.h>
#include <hip/hip_bf16.h>
#include <math.h>

#define NN 20000
#define NE 320000
#define NG 200
#define FI 75
#define NT 5
#define FO 15
#define CH 375     // NT*FI
#define PI 975
#define SMS 1608   // LDS stats row stride (ushorts): 16B-aligned, 2-way-free banks

typedef __attribute__((ext_vector_type(8))) short v8s;
typedef __attribute__((ext_vector_type(4))) float v4f;

__device__ __forceinline__ unsigned short f2bfu(float v) {
  __hip_bfloat16 h = __float2bfloat16(v);
  return *reinterpret_cast<unsigned short*>(&h);
}
__device__ __forceinline__ float uif(unsigned u) { return __uint_as_float(u); }

// ================= prep mega kernels =================
// mega1 (256 thr): gather_x | count | table_e | repack_WAs | make_V | bias_comb
__global__ __launch_bounds__(256) void k_mega1(
    const int* __restrict__ xidx, const float* __restrict__ emb, float* __restrict__ x,
    const int* __restrict__ dstp, int* __restrict__ deg,
    const float* __restrict__ eemb, const float* __restrict__ W_edge,
    const float* __restrict__ b_edge, float* __restrict__ te,
    const float* __restrict__ W_pre, float* __restrict__ WAs,
    const float* __restrict__ W_post, float* __restrict__ V,
    const float* __restrict__ b_post, const float* __restrict__ W_lin,
    const float* __restrict__ b_lin, float* __restrict__ bc) {
  __shared__ float S[FI * 16];
  int b = blockIdx.x, tid = threadIdx.x;
  if (b < 5860) {                       // gather_x
    int i = b * 256 + tid;
    if (i < NN * FI) {
      int n = i / FI, f = i - n * FI;
      x[i] = emb[xidx[n] * FI + f];
    }
  } else if (b < 7110) {                // count
    int e = (b - 5860) * 256 + tid;
    if (e < NE) atomicAdd(&deg[dstp[e]], 1);
  } else if (b < 7310) {                // table_e
    int la = b - 7110;
    int l = la / 100, a = la - l * 100;
    int f = tid;
    if (f < FI) {
      float acc = b_edge[l * FI + f];
      for (int j = 0; j < 50; ++j)
        acc = fmaf(eemb[a * 50 + j], W_edge[(l * 50 + j) * FI + f], acc);
      te[la * FI + f] = acc;
    }
  } else if (b < 7530) {                // repack_WAs
    int i = (b - 7310) * 256 + tid;
    if (i < 2 * FI * CH) {
      int c = i % CH;
      int k = (i / CH) % FI;
      int l = i / (CH * FI);
      int t = c / FI, f = c - t * FI;
      WAs[i] = W_pre[((size_t)(l * NT + t) * 225 + FI + k) * FI + f];
    }
  } else if (b < 7560) {                // make_V
    int bid = b - 7530;                 // (l*5+t)*3+g
    int g = bid % 3;
    int lt = bid / 3;
    for (int idx = tid; idx < FI * 16; idx += 256) {
      int q = idx >> 4, f = idx & 15;
      float v = 0.f;
      if (f < FO) {
        const float* wb = W_post + (size_t)lt * PI * FO;
        int rowb = FI + g * 300 + q;
        v = wb[rowb * FO + f] + wb[(rowb + FI) * FO + f] + wb[(rowb + 2 * FI) * FO + f];
      }
      S[idx] = v;
    }
    __syncthreads();
    for (int idx = tid; idx < FI * 16; idx += 256) {
      int j = idx >> 4, f = idx & 15;
      float acc = 0.f;
      const float* wr = W_pre + ((size_t)lt * 225 + j) * FI;
      for (int q = 0; q < FI; ++q) acc = fmaf(wr[q], S[q * 16 + f], acc);
      V[((size_t)bid * FI + j) * 16 + f] = acc;
    }
  } else {                              // bias_comb
    int l = b - 7560;
    int g = tid;
    if (g < FI) {
      float acc = b_lin[l * FI + g];
      for (int j = 0; j < FI; ++j)
        acc = fmaf(b_post[l * FI + j], W_lin[(l * FI + j) * FI + g], acc);
      bc[l * 76 + g] = acc;
    }
  }
}

// mega2 (1024 thr): scan | logsum | tbl_m | pack_B | pack_Bxs | pack_Blin
__global__ __launch_bounds__(1024) void k_mega2(
    const int* __restrict__ deg, int* __restrict__ off, int* __restrict__ cur,
    float* __restrict__ avglog,
    const float* __restrict__ te, const float* __restrict__ W_pre,
    const float* __restrict__ b_pre, unsigned short* __restrict__ tm,
    const float* __restrict__ W_post, const float* __restrict__ V,
    unsigned short* __restrict__ Bp,
    const float* __restrict__ WAs, unsigned short* __restrict__ Bxs,
    const float* __restrict__ W_lin, unsigned short* __restrict__ Blin) {
  __shared__ float red[1024];
  int b = blockIdx.x, t = threadIdx.x;
  if (b == 0) {                         // scan: 1024 x 20
    int* wsum = (int*)red;
    int base = t * 20;
    int loc[20];
    int s = 0;
#pragma unroll
    for (int j = 0; j < 20; ++j) {
      int i = base + j;
      int v = (i < NN) ? deg[i] : 0;
      loc[j] = s;
      s += v;
    }
    int lane = t & 63, w = t >> 6;
    int inc = s;
    for (int o = 1; o < 64; o <<= 1) {
      int u = __shfl_up(inc, o, 64);
      if (lane >= o) inc += u;
    }
    if (lane == 63) wsum[w] = inc;
    __syncthreads();
    if (t == 0) {
      int a = 0;
#pragma unroll
      for (int k = 0; k < 16; ++k) { int v = wsum[k]; wsum[k] = a; a += v; }
    }
    __syncthreads();
    int tex = wsum[w] + inc - s;
#pragma unroll
    for (int j = 0; j < 20; ++j) {
      int i = base + j;
      if (i < NN) { int e = tex + loc[j]; off[i] = e; cur[i] = e; }
    }
    if (t == 1023) off[NN] = tex + s;
  } else if (b == 1) {                  // logsum
    float s = 0.f;
    for (int i = t; i < NN; i += 1024) s += logf((float)deg[i] + 1.f);
    red[t] = s;
    __syncthreads();
    for (int o = 512; o > 0; o >>= 1) {
      if (t < o) red[t] += red[t + o];
      __syncthreads();
    }
    if (t == 0) avglog[0] = red[0] / (float)NN;
  } else if (b < 77) {                  // tbl_m flat: 2*100*384
    int idx = (b - 2) * 1024 + t;
    if (idx < 76800) {
      int la = idx / 384, c = idx - la * 384;
      int l = la / 100;
      float acc = 0.f;
      if (c < CH) {
        int tt = c / FI, f = c - tt * FI;
        acc = b_pre[(l * NT + tt) * FI + f];
        const float* ter = te + la * FI;
        for (int k = 0; k < FI; ++k)
          acc = fmaf(ter[k], W_pre[((size_t)(l * NT + tt) * 225 + 150 + k) * FI + f], acc);
      }
      tm[(size_t)la * 384 + c] = f2bfu(acc);
    }
  } else if (b < 302) {                 // pack_B (post MFMA weights)
    int i = (b - 77) * 1024 + t;
    if (i < 230400) {
      int j = i & 7;
      int lane = (i >> 3) & 63;
      int rem = i >> 9;
      int kb = rem % 15; rem /= 15;
      int g = rem % 3; rem /= 3;
      int tt = rem % 5;
      int l = rem / 5;
      int k = kb * 32 + (lane >> 4) * 8 + j;
      int f = lane & 15;
      float w = 0.f;
      if (f < FO) {
        int lt = l * NT + tt;
        if (k < 300) {
          int a = k / 75, ch = k - a * 75;
          w = W_post[((size_t)lt * PI + FI + g * 300 + a * 75 + ch) * FO + f];
        } else if (k >= 320 && k < 395) {
          w = V[(((size_t)(lt * 3 + g)) * FI + (k - 320)) * 16 + f];
        } else if (k >= 395 && k < 470 && g == 0) {
          w = W_post[((size_t)lt * PI + (k - 395)) * FO + f];
        }
      }
      Bp[i] = f2bfu(w);
    }
  } else if (b < 374) {                 // pack_Bxs (xs MFMA weights), 73728 elems
    int i = (b - 302) * 1024 + t;
    if (i < 73728) {
      int j = i & 7;
      int lane = (i >> 3) & 63;
      int rem = i >> 9;                 // 0..143
      int nt = rem % 24; rem /= 24;
      int kb = rem % 3;
      int l = rem / 3;
      int k = kb * 32 + (lane >> 4) * 8 + j;
      int n = nt * 16 + (lane & 15);
      float w = 0.f;
      if (k < FI && n < CH) w = WAs[(size_t)l * FI * CH + k * CH + n];
      Bxs[i] = f2bfu(w);
    }
  } else {                              // pack_Blin (W_lin MFMA weights), 15360 elems
    int i = (b - 374) * 1024 + t;
    if (i < 15360) {
      int j = i & 7;
      int lane = (i >> 3) & 63;
      int rem = i >> 9;                 // 0..29
      int nt = rem % 5; rem /= 5;
      int kb = rem % 3;
      int l = rem / 3;
      int k = kb * 32 + (lane >> 4) * 8 + j;
      int f = nt * 16 + (lane & 15);
      float w = 0.f;
      if (k < FI && f < FI) w = W_lin[(size_t)l * FI * FI + k * FI + f];
      Blin[i] = f2bfu(w);
    }
  }
}

// mega3 (256 thr): fill | scalers
__global__ __launch_bounds__(256) void k_mega3(
    const int* __restrict__ srcp, const int* __restrict__ dstp,
    const int* __restrict__ attr, int* __restrict__ cur, int2* __restrict__ csr,
    const int* __restrict__ deg, const float* __restrict__ avglog,
    float* __restrict__ amp, float* __restrict__ att, float* __restrict__ inv) {
  int b = blockIdx.x, t = threadIdx.x;
  if (b < 1250) {
    int e = b * 256 + t;
    if (e < NE) {
      int pos = atomicAdd(&cur[dstp[e]], 1);
      csr[pos] = make_int2(srcp[e], attr[e]);
    }
  } else {
    int i = (b - 1250) * 256 + t;
    if (i < NN) {
      float dc = fmaxf((float)deg[i], 1.f);
      float ld = logf(dc + 1.f);
      float av = avglog[0];
      amp[i] = ld / av;
      att[i] = av / ld;
      inv[i] = 1.f / dc;
    }
  }
}

// ================= per-layer =================
// prepx: build xh (self-feature rows for phase2) + xq (bf16 x rows, 96-wide, for
// the in-aggpost MFMA expansion) + zero bnsum. Replaces the old xs GEMM entirely.
__global__ __launch_bounds__(256) void k_prepx(const float* __restrict__ x,
                                               const int* __restrict__ deg,
                                               unsigned short* __restrict__ xh,
                                               unsigned short* __restrict__ xq,
                                               float* __restrict__ bnsum) {
  int tid = threadIdx.x;
  if (blockIdx.x == 0 && tid < 150) bnsum[tid] = 0.f;
  for (int i = blockIdx.x * 256 + tid; i < NN * 160; i += 625 * 256) {
    int r = i / 160, k = i - r * 160;
    float v = 0.f;
    if (k < FI) v = x[(size_t)r * FI + k] * ((deg[r] > 0) ? 1.f : 0.f);
    else if (k < 150) v = x[(size_t)r * FI + k - FI];
    xh[i] = f2bfu(v);
  }
  for (int i = blockIdx.x * 256 + tid; i < NN * 96; i += 625 * 256) {
    int r = i / 96, k = i - r * 96;
    xq[i] = (k < FI) ? f2bfu(x[(size_t)r * FI + k]) : 0;
  }
}

// fused aggregate+post: block = 1024 thr (16 waves) = 16 nodes.
// phase1 (MFMA expansion): R1-R6 proved the 768B xs-row gather is fabric-bound
// at ~5 TB/s (xs table 15.4MB >> 4MB/XCD L2; FETCH ~103MB = each XCD refetching
// the table). Fix: gather only 192B xq rows (table 3.8MB, L2-resident) and
// expand per 16-edge tile via MFMA: A = staged xq rows (104-stride layout as in
// the old xs GEMM), B = existing Bxs fragments held in registers (wave w owns
// nt {2w,2w+1} for w<8, {w+8} for w>=8), tm added from an LDS copy. Stats per
// lane-column with validity masking; shfl_xor quad-reduce at node end -> sm.
// Block-synchronous tiles, double-buffered A, T14 issue-early/write-late staging
// by waves 13..15. Fabric bytes/edge: 1536 -> ~192.
// phase2: waves 0..4 = towers, A from LDS, 15 kb MFMAs x3 groups -> z bf16 LDS.
// phase3: waves 0..4: y cols [t*16,t*16+16) = z@W_lin + bc -> global + BN partials.
__global__ __launch_bounds__(1024) void k_aggpost(
    const unsigned short* __restrict__ xq, const int2* __restrict__ csr,
    const int* __restrict__ off, const float* __restrict__ inv_deg,
    const unsigned short* __restrict__ tm, const unsigned short* __restrict__ xh,
    const unsigned short* __restrict__ Bp, const float* __restrict__ amp,
    const float* __restrict__ att, const unsigned short* __restrict__ BlinL,
    const float* __restrict__ bcL, float* __restrict__ yout,
    float* __restrict__ bnsum, const unsigned short* __restrict__ BxsL) {
  __shared__ __align__(16) unsigned short tml[100 * 384];   // 76.8 KB tm table
  __shared__ __align__(16) unsigned short sm[16 * SMS];     // ~50.3 KB
  __shared__ __align__(16) unsigned short zs[16 * 96];      // 3 KB
  __shared__ __align__(16) unsigned short As0[16 * 104];    // A tile buf 0 (3.3 KB)
  __shared__ __align__(16) unsigned short As1[16 * 104];    // A tile buf 1
  __shared__ int offL[17];
  __shared__ int cumT[17];
  __shared__ float ysum[FI], ysq[FI];
  int tid = threadIdx.x;
  int wv = tid >> 6, lane = tid & 63;
  int m16 = lane & 15, quad = lane >> 4;
  int rel0 = blockIdx.x * 16;
  // ---- preload ----
  if (tid < 17) offL[tid] = off[rel0 + tid];
  if (tid < FI) { ysum[tid] = 0.f; ysq[tid] = 0.f; }
  for (int idx = tid; idx < 1600; idx += 1024) {   // zero per-tower pads (16 rows)
    int h = idx / 100, pp = idx - h * 100;
    int t = pp / 20, cc = pp - t * 20;
    sm[h * SMS + t * 320 + 300 + cc] = 0;
  }
  for (int i = tid; i < 16 * 21; i += 1024) {      // zero zs k-pad cols 75..95
    int r = i / 21, k = 75 + i - r * 21;
    zs[r * 96 + k] = 0;
  }
  {                                                 // stage tm table -> LDS
    const uint4* ts = (const uint4*)tm;
    uint4* td = (uint4*)tml;
    for (int i = tid; i < 4800; i += 1024) td[i] = ts[i];
  }
  __syncthreads();
  if (tid == 0) {                                   // tile prefix over 16 nodes
    int a = 0;
#pragma unroll
    for (int i = 0; i < 16; ++i) {
      cumT[i] = a;
      a += (offL[i + 1] - offL[i] + 15) >> 4;
    }
    cumT[16] = a;
  }
  // wave's owned column tiles + persistent B fragments (from existing Bxs pack)
  int nt0 = (wv < 8) ? 2 * wv : 8 + wv;
  v8s Bf00, Bf01, Bf02, Bf10, Bf11, Bf12;
  Bf00 = *(const v8s*)(BxsL + ((size_t)(0 * 24 + nt0) * 64 + lane) * 8);
  Bf01 = *(const v8s*)(BxsL + ((size_t)(1 * 24 + nt0) * 64 + lane) * 8);
  Bf02 = *(const v8s*)(BxsL + ((size_t)(2 * 24 + nt0) * 64 + lane) * 8);
  if (wv < 8) {
    Bf10 = *(const v8s*)(BxsL + ((size_t)(0 * 24 + nt0 + 1) * 64 + lane) * 8);
    Bf11 = *(const v8s*)(BxsL + ((size_t)(1 * 24 + nt0 + 1) * 64 + lane) * 8);
    Bf12 = *(const v8s*)(BxsL + ((size_t)(2 * 24 + nt0 + 1) * 64 + lane) * 8);
  } else { Bf10 = Bf00; Bf11 = Bf01; Bf12 = Bf02; }
  // empty nodes: write their sm rows now (mirrors old empty handling)
  {
    float sd0 = sqrtf(1e-5f);
    for (int i = 0; i < 16; ++i) {
      if (offL[i + 1] == offL[i] && quad == 0) {
#pragma unroll
        for (int t2 = 0; t2 < 2; ++t2) {
          if (t2 == 0 || wv < 8) {
            int col = (nt0 + t2) * 16 + m16;
            if (col < CH) {
              int tcol = col / 75, ch = col - tcol * 75;
              unsigned short* bb = sm + i * SMS + tcol * 320;
              bb[ch] = 0; bb[75 + ch] = 0; bb[150 + ch] = 0; bb[225 + ch] = f2bfu(sd0);
            }
          }
        }
      }
    }
  }
  __syncthreads();
  // ---- phase 1 main loop ----
  float sA0 = 0.f, qA0 = 0.f, mnA0 = INFINITY, mxA0 = -INFINITY;
  float sA1 = 0.f, qA1 = 0.f, mnA1 = INFINITY, mxA1 = -INFINITY;
  int T = cumT[16];
  int ci = 0, si = 0;
  if (T > 0) {                                      // prologue: stage tile 0
    while (0 >= cumT[si + 1]) ++si;
    if (tid >= 832) {
      int tid2 = tid - 832;
      int base = offL[si];                          // tile 0 of node si
      int e = base + tid2 / 12;
      int o1m1 = offL[si + 1] - 1;
      if (e > o1m1) e = o1m1;
      int c16 = tid2 % 12;
      int2 ec = csr[e];
      *(uint4*)&As0[(tid2 / 12) * 104 + c16 * 8] =
          *(const uint4*)&xq[(size_t)ec.x * 96 + c16 * 8];
    }
  }
  __syncthreads();
  for (int t = 0; t < T; ++t) {
    unsigned short* Acur = (t & 1) ? As1 : As0;
    unsigned short* Anxt = (t & 1) ? As0 : As1;
    // issue next-tile staged loads (write-late after compute)
    uint4 sval;
    bool doStage = (t + 1 < T) && (tid >= 832);
    if (t + 1 < T) { while (t + 1 >= cumT[si + 1]) ++si; }
    if (doStage) {
      int tid2 = tid - 832;
      int base = offL[si] + (t + 1 - cumT[si]) * 16;
      int e = base + tid2 / 12;
      int o1m1 = offL[si + 1] - 1;
      if (e > o1m1) e = o1m1;
      int2 ec = csr[e];
      sval = *(const uint4*)&xq[(size_t)ec.x * 96 + (tid2 % 12) * 8];
    }
    // compute tile t
    while (t >= cumT[ci + 1]) ++ci;
    int o0i = offL[ci], o1i = offL[ci + 1];
    int base = o0i + (t - cumT[ci]) * 16;
    int o1m1 = o1i - 1;
    v8s av0 = *(const v8s*)(Acur + m16 * 104 + quad * 8);
    v8s av1 = *(const v8s*)(Acur + m16 * 104 + 32 + quad * 8);
    v8s av2 = *(const v8s*)(Acur + m16 * 104 + 64 + quad * 8);
    int er = base + quad * 4;
    int i0 = er, i1 = er + 1, i2 = er + 2, i3 = er + 3;
    bool v0 = i0 <= o1m1, v1 = i1 <= o1m1, v2 = i2 <= o1m1, v3 = i3 <= o1m1;
    if (i0 > o1m1) i0 = o1m1;
    if (i1 > o1m1) i1 = o1m1;
    if (i2 > o1m1) i2 = o1m1;
    if (i3 > o1m1) i3 = o1m1;
    int a0 = csr[i0].y, a1 = csr[i1].y, a2 = csr[i2].y, a3 = csr[i3].y;
    {
      v4f acc = {0.f, 0.f, 0.f, 0.f};
      acc = __builtin_amdgcn_mfma_f32_16x16x32_bf16(av0, Bf00, acc, 0, 0, 0);
      acc = __builtin_amdgcn_mfma_f32_16x16x32_bf16(av1, Bf01, acc, 0, 0, 0);
      acc = __builtin_amdgcn_mfma_f32_16x16x32_bf16(av2, Bf02, acc, 0, 0, 0);
      int col = nt0 * 16 + m16;
      float z0 = acc[0] + uif((unsigned)tml[a0 * 384 + col] << 16);
      float z1 = acc[1] + uif((unsigned)tml[a1 * 384 + col] << 16);
      float z2 = acc[2] + uif((unsigned)tml[a2 * 384 + col] << 16);
      float z3 = acc[3] + uif((unsigned)tml[a3 * 384 + col] << 16);
      sA0 += (v0 ? z0 : 0.f) + (v1 ? z1 : 0.f) + (v2 ? z2 : 0.f) + (v3 ? z3 : 0.f);
      qA0 = v0 ? fmaf(z0, z0, qA0) : qA0;  qA0 = v1 ? fmaf(z1, z1, qA0) : qA0;
      qA0 = v2 ? fmaf(z2, z2, qA0) : qA0;  qA0 = v3 ? fmaf(z3, z3, qA0) : qA0;
      mnA0 = v0 ? fminf(mnA0, z0) : mnA0;  mnA0 = v1 ? fminf(mnA0, z1) : mnA0;
      mnA0 = v2 ? fminf(mnA0, z2) : mnA0;  mnA0 = v3 ? fminf(mnA0, z3) : mnA0;
      mxA0 = v0 ? fmaxf(mxA0, z0) : mxA0;  mxA0 = v1 ? fmaxf(mxA0, z1) : mxA0;
      mxA0 = v2 ? fmaxf(mxA0, z2) : mxA0;  mxA0 = v3 ? fmaxf(mxA0, z3) : mxA0;
    }
    if (wv < 8) {
      v4f acc = {0.f, 0.f, 0.f, 0.f};
      acc = __builtin_amdgcn_mfma_f32_16x16x32_bf16(av0, Bf10, acc, 0, 0, 0);
      acc = __builtin_amdgcn_mfma_f32_16x16x32_bf16(av1, Bf11, acc, 0, 0, 0);
      acc = __builtin_amdgcn_mfma_f32_16x16x32_bf16(av2, Bf12, acc, 0, 0, 0);
      int col = (nt0 + 1) * 16 + m16;
      float z0 = acc[0] + uif((unsigned)tml[a0 * 384 + col] << 16);
      float z1 = acc[1] + uif((unsigned)tml[a1 * 384 + col] << 16);
      float z2 = acc[2] + uif((unsigned)tml[a2 * 384 + col] << 16);
      float z3 = acc[3] + uif((unsigned)tml[a3 * 384 + col] << 16);
      sA1 += (v0 ? z0 : 0.f) + (v1 ? z1 : 0.f) + (v2 ? z2 : 0.f) + (v3 ? z3 : 0.f);
      qA1 = v0 ? fmaf(z0, z0, qA1) : qA1;  qA1 = v1 ? fmaf(z1, z1, qA1) : qA1;
      qA1 = v2 ? fmaf(z2, z2, qA1) : qA1;  qA1 = v3 ? fmaf(z3, z3, qA1) : qA1;
      mnA1 = v0 ? fminf(mnA1, z0) : mnA1;  mnA1 = v1 ? fminf(mnA1, z1) : mnA1;
      mnA1 = v2 ? fminf(mnA1, z2) : mnA1;  mnA1 = v3 ? fminf(mnA1, z3) : mnA1;
      mxA1 = v0 ? fmaxf(mxA1, z0) : mxA1;  mxA1 = v1 ? fmaxf(mxA1, z1) : mxA1;
      mxA1 = v2 ? fmaxf(mxA1, z2) : mxA1;  mxA1 = v3 ? fmaxf(mxA1, z3) : mxA1;
    }
    // write staged tile t+1
    if (doStage) {
      int tid2 = tid - 832;
      *(uint4*)&Anxt[(tid2 / 12) * 104 + (tid2 % 12) * 8] = sval;
    }
    // node end: quad-reduce + write sm row, reset stats
    if (t == cumT[ci + 1] - 1) {
      float inv = inv_deg[rel0 + ci];
#pragma unroll
      for (int t2 = 0; t2 < 2; ++t2) {
        if (t2 == 1 && wv >= 8) break;
        float S = (t2 == 0) ? sA0 : sA1;
        float Q = (t2 == 0) ? qA0 : qA1;
        float MN = (t2 == 0) ? mnA0 : mnA1;
        float MX = (t2 == 0) ? mxA0 : mxA1;
        S += __shfl_xor(S, 16); S += __shfl_xor(S, 32);
        Q += __shfl_xor(Q, 16); Q += __shfl_xor(Q, 32);
        MN = fminf(MN, __shfl_xor(MN, 16)); MN = fminf(MN, __shfl_xor(MN, 32));
        MX = fmaxf(MX, __shfl_xor(MX, 16)); MX = fmaxf(MX, __shfl_xor(MX, 32));
        if (quad == 0) {
          int col = (nt0 + t2) * 16 + m16;
          if (col < CH) {
            float me = S * inv;
            float sd = sqrtf(fmaxf(Q * inv - me * me, 0.f) + 1e-5f);
            int tcol = col / 75, ch = col - tcol * 75;
            unsigned short* bb = sm + ci * SMS + tcol * 320;
            bb[ch] = f2bfu(me);
            bb[75 + ch] = f2bfu(MN);
            bb[150 + ch] = f2bfu(MX);
            bb[225 + ch] = f2bfu(sd);
          }
        }
      }
      sA0 = 0.f; qA0 = 0.f; mnA0 = INFINITY; mxA0 = -INFINITY;
      sA1 = 0.f; qA1 = 0.f; mnA1 = INFINITY; mxA1 = -INFINITY;
    }
    __syncthreads();
  }
  __syncthreads();
  // ---- phase 2: tower MFMA from LDS ----
  if (wv < NT) {
    int tw = wv;
    const unsigned short* arow = sm + m16 * SMS + tw * 320 + quad * 8;
    const unsigned short* xrow = xh + (size_t)(rel0 + m16) * 160 + quad * 8;
    const unsigned short* bp = Bp + ((size_t)tw * 3 * 15 * 64) * 8 + lane * 8;
    v4f a0 = {0.f, 0.f, 0.f, 0.f}, a1 = a0, a2 = a0;
#pragma unroll
    for (int kb = 0; kb < 15; ++kb) {
      v8s av = *(const v8s*)((kb < 10) ? (arow + kb * 32) : (xrow + (kb - 10) * 32));
      const unsigned short* bb = bp + (size_t)kb * 512;
      v8s b0 = *(const v8s*)(bb);
      v8s b1 = *(const v8s*)(bb + 15 * 512);
      v8s b2 = *(const v8s*)(bb + 30 * 512);
      a0 = __builtin_amdgcn_mfma_f32_16x16x32_bf16(av, b0, a0, 0, 0, 0);
      a1 = __builtin_amdgcn_mfma_f32_16x16x32_bf16(av, b1, a1, 0, 0, 0);
      a2 = __builtin_amdgcn_mfma_f32_16x16x32_bf16(av, b2, a2, 0, 0, 0);
    }
    int f = m16;
    if (f < FO) {
      int relZ = quad * 4;
#pragma unroll
      for (int r = 0; r < 4; ++r) {
        int nd = rel0 + relZ + r;
        int ndc = (nd < NN) ? nd : (NN - 1);
        float zz = a0[r] + amp[ndc] * a1[r] + att[ndc] * a2[r];
        zs[(relZ + r) * 96 + tw * FO + f] = f2bfu(zz);
      }
    }
  }
  __syncthreads();
  // ---- phase 3: y cols [tw*16, tw*16+16) ----
  if (wv < NT) {
    int tw = wv;
    v4f acc2 = {0.f, 0.f, 0.f, 0.f};
#pragma unroll
    for (int kb = 0; kb < 3; ++kb) {
      v8s av = *(const v8s*)(zs + m16 * 96 + quad * 8 + kb * 32);
      v8s bl = *(const v8s*)(BlinL + ((size_t)(kb * 5 + tw) * 64 + lane) * 8);
      acc2 = __builtin_amdgcn_mfma_f32_16x16x32_bf16(av, bl, acc2, 0, 0, 0);
    }
    int fcol = tw * 16 + m16;
    if (fcol < FI) {
      float bcf = bcL[fcol];
      int nb = rel0 + quad * 4;
#pragma unroll
      for (int r = 0; r < 4; ++r) {
        int nd = nb + r;
        if (nd < NN) {
          float v = acc2[r] + bcf;
          yout[(size_t)nd * FI + fcol] = v;
          atomicAdd(&ysum[fcol], v);
          atomicAdd(&ysq[fcol], v * v);
        }
      }
    }
  }
  __syncthreads();
  if (tid < FI) {
    atomicAdd(&bnsum[tid], ysum[tid]);
    atomicAdd(&bnsum[FI + tid], ysq[tid]);
  }
}

// BN finalize+apply; dopool==0: also zero pooled for next layer; dopool==1: pool.
__global__ __launch_bounds__(256) void k_bnfinapply(const float* __restrict__ y,
    const float* __restrict__ bnsum, const float* __restrict__ gamL,
    const float* __restrict__ betL, float* __restrict__ xo,
    const int* __restrict__ batch, float* __restrict__ pooled, int dopool) {
  __shared__ float sc[150];
  int tid = threadIdx.x;
  if (tid < FI) {
    float mu = bnsum[tid] / (float)NN;
    float var = bnsum[FI + tid] / (float)NN - mu * mu;
    float scl = gamL[tid] * rsqrtf(var + 1e-5f);
    sc[tid] = scl;
    sc[FI + tid] = betL[tid] - mu * scl;
  }
  if (!dopool) {
    for (int i = blockIdx.x * 256 + tid; i < NG * FI; i += gridDim.x * 256)
      pooled[i] = 0.f;
  }
  __syncthreads();
  int stride = gridDim.x * 256;
  for (int i = blockIdx.x * 256 + tid; i < NN * FI; i += stride) {
    int n = i / FI, f = i - n * FI;
    float v = fmaxf(fmaf(y[i], sc[f], sc[FI + f]), 0.f);
    xo[i] = v;
    if (dopool) atomicAdd(&pooled[batch[n] * FI + f], v);
  }
}

__global__ void k_head(const float* __restrict__ pooled, const float* __restrict__ W1,
                       const float* __restrict__ b1, const float* __restrict__ W2,
                       const float* __restrict__ b2, const float* __restrict__ W3,
                       const float* __restrict__ b3, float* __restrict__ out) {
  __shared__ float p[FI], h1[50], h2[25];
  int g = blockIdx.x, t = threadIdx.x;
  for (int i = t; i < FI; i += 64) p[i] = pooled[g * FI + i];
  __syncthreads();
  if (t < 50) {
    float a = b1[t];
    for (int j = 0; j < FI; ++j) a = fmaf(p[j], W1[j * 50 + t], a);
    h1[t] = fmaxf(a, 0.f);
  }
  __syncthreads();
  if (t < 25) {
    float a = b2[t];
    for (int j = 0; j < 50; ++j) a = fmaf(h1[j], W2[j * 25 + t], a);
    h2[t] = fmaxf(a, 0.f);
  }
  __syncthreads();
  if (t == 0) {
    float a = b3[0];
    for (int j = 0; j < 25; ++j) a = fmaf(h2[j], W3[j], a);
    out[g] = a;
  }
}

extern "C" void kernel_launch(void* const* d_in, const int* in_sizes, int n_in,
                              void* d_out, int out_size, void* d_ws, size_t ws_size,
                              hipStream_t stream) {
  const int* x_idx = (const int*)d_in[0];
  const int* eidx  = (const int*)d_in[1];
  const int* srcp  = eidx;
  const int* dstp  = eidx + NE;
  const int* eattr = (const int*)d_in[2];
  const int* batch = (const int*)d_in[3];
  const float* node_emb = (const float*)d_in[4];
  const float* edge_emb = (const float*)d_in[5];
  const float* W_edge = (const float*)d_in[6];
  const float* b_edge = (const float*)d_in[7];
  const float* W_pre  = (const float*)d_in[8];
  const float* b_pre  = (const float*)d_in[9];
  const float* W_post = (const float*)d_in[10];
  const float* b_post = (const float*)d_in[11];
  const float* W_lin  = (const float*)d_in[12];
  const float* b_lin  = (const float*)d_in[13];
  const float* gam = (const float*)d_in[14];
  const float* bet = (const float*)d_in[15];
  const float* W1 = (const float*)d_in[16];
  const float* b1 = (const float*)d_in[17];
  const float* W2 = (const float*)d_in[18];
  const float* b2 = (const float*)d_in[19];
  const float* W3 = (const float*)d_in[20];
  const float* b3 = (const float*)d_in[21];

  char* p = (char*)d_ws;
  auto alloc = [&](size_t b) -> char* {
    char* r = p;
    p += (b + 255) & ~(size_t)255;
    return r;
  };
  float* x_a   = (float*)alloc((size_t)NN * FI * 4);
  float* x_b   = (float*)alloc((size_t)NN * FI * 4);
  unsigned short* xq = (unsigned short*)alloc((size_t)NN * 96 * 2);
  float* z     = (float*)alloc((size_t)NN * FI * 4);
  unsigned short* xh = (unsigned short*)alloc((size_t)(NN + 64) * 160 * 2);
  float* te    = (float*)alloc(2 * 100 * FI * 4);
  unsigned short* tm_bf = (unsigned short*)alloc((size_t)2 * 100 * 384 * 2);
  float* WAs   = (float*)alloc((size_t)2 * FI * CH * 4);
  float* V     = (float*)alloc((size_t)2 * NT * 3 * FI * 16 * 4);
  unsigned short* Bpk = (unsigned short*)alloc((size_t)230400 * 2);
  unsigned short* Bxs = (unsigned short*)alloc((size_t)73728 * 2);
  unsigned short* Blin = (unsigned short*)alloc((size_t)15360 * 2);
  float* bc    = (float*)alloc(2 * 76 * 4);
  float* ampv  = (float*)alloc((size_t)NN * 4);
  float* attv  = (float*)alloc((size_t)NN * 4);
  float* invv  = (float*)alloc((size_t)NN * 4);
  float* avglog = (float*)alloc(256);
  float* bnsum = (float*)alloc(2 * FI * 4);
  float* pooled = (float*)alloc((size_t)NG * FI * 4);
  int* deg = (int*)alloc((size_t)NN * 4);
  int* off = (int*)alloc((size_t)(NN + 1) * 4);
  int* cur = (int*)alloc((size_t)NN * 4);
  int2* csr = (int2*)alloc((size_t)NE * 8);

  hipMemsetAsync(deg, 0, (size_t)NN * 4, stream);

  k_mega1<<<7562, 256, 0, stream>>>(x_idx, node_emb, x_a, dstp, deg,
                                    edge_emb, W_edge, b_edge, te,
                                    W_pre, WAs, W_post, V,
                                    b_post, W_lin, b_lin, bc);
  k_mega2<<<389, 1024, 0, stream>>>(deg, off, cur, avglog,
                                    te, W_pre, b_pre, tm_bf, W_post, V, Bpk,
                                    WAs, Bxs, W_lin, Blin);
  k_mega3<<<1329, 256, 0, stream>>>(srcp, dstp, eattr, cur, csr,
                                    deg, avglog, ampv, attv, invv);

  for (int l = 0; l < 2; ++l) {
    const float* xin = (l == 0) ? x_a : x_b;
    float* xout = (l == 0) ? x_b : x_a;
    k_prepx<<<625, 256, 0, stream>>>(xin, deg, xh, xq, bnsum);
    k_aggpost<<<1250, 1024, 0, stream>>>(xq, csr, off, invv,
                                         tm_bf + (size_t)l * 100 * 384, xh,
                                         Bpk + (size_t)l * 115200, ampv, attv,
                                         Blin + (size_t)l * 7680, bc + l * 76,
                                         z, bnsum, Bxs + (size_t)l * 36864);
    k_bnfinapply<<<1250, 256, 0, stream>>>(z, bnsum, gam + l * FI, bet + l * FI,
                                           xout, batch, pooled, (l == 1) ? 1 : 0);
  }

  k_head<<<NG, 64, 0, stream>>>(pooled, W1, b1, W2, b2, W3, b3, (float*)d_out);
}

// Round 8
// 679.432 us; speedup vs baseline: 1.0798x; 1.0798x over previous
//
#include <hip/hip_runtime.h>
#include <hip/hip_bf16.h>
#include <math.h>

#define NN 20000
#define NE 320000
#define NG 200
#define FI 75
#define NT 5
#define FO 15
#define CH 375     // NT*FI
#define PI 975
#define SMS 1608   // LDS stats row stride (ushorts): 16B-aligned, 2-way-free banks

typedef __attribute__((ext_vector_type(8))) short v8s;
typedef __attribute__((ext_vector_type(4))) float v4f;

__device__ __forceinline__ unsigned short f2bfu(float v) {
  __hip_bfloat16 h = __float2bfloat16(v);
  return *reinterpret_cast<unsigned short*>(&h);
}
__device__ __forceinline__ float uif(unsigned u) { return __uint_as_float(u); }

// ================= prep mega kernels =================
// mega1 (256 thr): gather_x | count | table_e | repack_WAs | make_V | bias_comb
__global__ __launch_bounds__(256) void k_mega1(
    const int* __restrict__ xidx, const float* __restrict__ emb, float* __restrict__ x,
    const int* __restrict__ dstp, int* __restrict__ deg,
    const float* __restrict__ eemb, const float* __restrict__ W_edge,
    const float* __restrict__ b_edge, float* __restrict__ te,
    const float* __restrict__ W_pre, float* __restrict__ WAs,
    const float* __restrict__ W_post, float* __restrict__ V,
    const float* __restrict__ b_post, const float* __restrict__ W_lin,
    const float* __restrict__ b_lin, float* __restrict__ bc) {
  __shared__ float S[FI * 16];
  int b = blockIdx.x, tid = threadIdx.x;
  if (b < 5860) {                       // gather_x
    int i = b * 256 + tid;
    if (i < NN * FI) {
      int n = i / FI, f = i - n * FI;
      x[i] = emb[xidx[n] * FI + f];
    }
  } else if (b < 7110) {                // count
    int e = (b - 5860) * 256 + tid;
    if (e < NE) atomicAdd(&deg[dstp[e]], 1);
  } else if (b < 7310) {                // table_e
    int la = b - 7110;
    int l = la / 100, a = la - l * 100;
    int f = tid;
    if (f < FI) {
      float acc = b_edge[l * FI + f];
      for (int j = 0; j < 50; ++j)
        acc = fmaf(eemb[a * 50 + j], W_edge[(l * 50 + j) * FI + f], acc);
      te[la * FI + f] = acc;
    }
  } else if (b < 7530) {                // repack_WAs
    int i = (b - 7310) * 256 + tid;
    if (i < 2 * FI * CH) {
      int c = i % CH;
      int k = (i / CH) % FI;
      int l = i / (CH * FI);
      int t = c / FI, f = c - t * FI;
      WAs[i] = W_pre[((size_t)(l * NT + t) * 225 + FI + k) * FI + f];
    }
  } else if (b < 7560) {                // make_V
    int bid = b - 7530;                 // (l*5+t)*3+g
    int g = bid % 3;
    int lt = bid / 3;
    for (int idx = tid; idx < FI * 16; idx += 256) {
      int q = idx >> 4, f = idx & 15;
      float v = 0.f;
      if (f < FO) {
        const float* wb = W_post + (size_t)lt * PI * FO;
        int rowb = FI + g * 300 + q;
        v = wb[rowb * FO + f] + wb[(rowb + FI) * FO + f] + wb[(rowb + 2 * FI) * FO + f];
      }
      S[idx] = v;
    }
    __syncthreads();
    for (int idx = tid; idx < FI * 16; idx += 256) {
      int j = idx >> 4, f = idx & 15;
      float acc = 0.f;
      const float* wr = W_pre + ((size_t)lt * 225 + j) * FI;
      for (int q = 0; q < FI; ++q) acc = fmaf(wr[q], S[q * 16 + f], acc);
      V[((size_t)bid * FI + j) * 16 + f] = acc;
    }
  } else {                              // bias_comb
    int l = b - 7560;
    int g = tid;
    if (g < FI) {
      float acc = b_lin[l * FI + g];
      for (int j = 0; j < FI; ++j)
        acc = fmaf(b_post[l * FI + j], W_lin[(l * FI + j) * FI + g], acc);
      bc[l * 76 + g] = acc;
    }
  }
}

// mega2 (1024 thr): scan | logsum | tq | pack_Bx2 (K=160) | pack_B | pack_Blin
__global__ __launch_bounds__(1024) void k_mega2(
    const int* __restrict__ deg, int* __restrict__ off, int* __restrict__ cur,
    float* __restrict__ avglog,
    const float* __restrict__ te, unsigned short* __restrict__ tq,
    const float* __restrict__ W_pre,
    const float* __restrict__ W_post, const float* __restrict__ V,
    unsigned short* __restrict__ Bp,
    const float* __restrict__ WAs, unsigned short* __restrict__ Bx2,
    const float* __restrict__ W_lin, unsigned short* __restrict__ Blin) {
  __shared__ float red[1024];
  int b = blockIdx.x, t = threadIdx.x;
  if (b == 0) {                         // scan: 1024 x 20
    int* wsum = (int*)red;
    int base = t * 20;
    int loc[20];
    int s = 0;
#pragma unroll
    for (int j = 0; j < 20; ++j) {
      int i = base + j;
      int v = (i < NN) ? deg[i] : 0;
      loc[j] = s;
      s += v;
    }
    int lane = t & 63, w = t >> 6;
    int inc = s;
    for (int o = 1; o < 64; o <<= 1) {
      int u = __shfl_up(inc, o, 64);
      if (lane >= o) inc += u;
    }
    if (lane == 63) wsum[w] = inc;
    __syncthreads();
    if (t == 0) {
      int a = 0;
#pragma unroll
      for (int k = 0; k < 16; ++k) { int v = wsum[k]; wsum[k] = a; a += v; }
    }
    __syncthreads();
    int tex = wsum[w] + inc - s;
#pragma unroll
    for (int j = 0; j < 20; ++j) {
      int i = base + j;
      if (i < NN) { int e = tex + loc[j]; off[i] = e; cur[i] = e; }
    }
    if (t == 1023) off[NN] = tex + s;
  } else if (b == 1) {                  // logsum
    float s = 0.f;
    for (int i = t; i < NN; i += 1024) s += logf((float)deg[i] + 1.f);
    red[t] = s;
    __syncthreads();
    for (int o = 512; o > 0; o >>= 1) {
      if (t < o) red[t] += red[t + o];
      __syncthreads();
    }
    if (t == 0) avglog[0] = red[0] / (float)NN;
  } else if (b < 18) {                  // tq: bf16 te table, 80-wide (2*100*80)
    int idx = (b - 2) * 1024 + t;
    if (idx < 16000) {
      int la = idx / 80, k = idx - la * 80;
      tq[idx] = (k < FI) ? f2bfu(te[la * FI + k]) : 0;
    }
  } else if (b < 138) {                 // pack_Bx2: K=160 expansion weights
    int i = (b - 18) * 1024 + t;
    if (i < 122880) {
      int j = i & 7;
      int lane = (i >> 3) & 63;
      int rem = i >> 9;                 // 0..239 = (l*5+kb)*24 + nt
      int nt = rem % 24; rem /= 24;
      int kb = rem % 5;
      int l = rem / 5;
      int k = kb * 32 + (lane >> 4) * 8 + j;
      int n = nt * 16 + (lane & 15);
      float w = 0.f;
      if (n < CH) {
        if (k < FI) {
          w = WAs[(size_t)l * FI * CH + k * CH + n];        // src block
        } else if (k >= 80 && k < 80 + FI) {
          int tt = n / 75, f = n - tt * 75;                 // edge block
          w = W_pre[((size_t)(l * NT + tt) * 225 + 150 + (k - 80)) * FI + f];
        }
      }
      Bx2[i] = f2bfu(w);
    }
  } else if (b < 363) {                 // pack_B (post MFMA weights)
    int i = (b - 138) * 1024 + t;
    if (i < 230400) {
      int j = i & 7;
      int lane = (i >> 3) & 63;
      int rem = i >> 9;
      int kb = rem % 15; rem /= 15;
      int g = rem % 3; rem /= 3;
      int tt = rem % 5;
      int l = rem / 5;
      int k = kb * 32 + (lane >> 4) * 8 + j;
      int f = lane & 15;
      float w = 0.f;
      if (f < FO) {
        int lt = l * NT + tt;
        if (k < 300) {
          int a = k / 75, ch = k - a * 75;
          w = W_post[((size_t)lt * PI + FI + g * 300 + a * 75 + ch) * FO + f];
        } else if (k >= 320 && k < 395) {
          w = V[(((size_t)(lt * 3 + g)) * FI + (k - 320)) * 16 + f];
        } else if (k >= 395 && k < 470 && g == 0) {
          w = W_post[((size_t)lt * PI + (k - 395)) * FO + f];
        }
      }
      Bp[i] = f2bfu(w);
    }
  } else {                              // pack_Blin, 15360 elems
    int i = (b - 363) * 1024 + t;
    if (i < 15360) {
      int j = i & 7;
      int lane = (i >> 3) & 63;
      int rem = i >> 9;                 // 0..29
      int nt = rem % 5; rem /= 5;
      int kb = rem % 3;
      int l = rem / 3;
      int k = kb * 32 + (lane >> 4) * 8 + j;
      int f = nt * 16 + (lane & 15);
      float w = 0.f;
      if (k < FI && f < FI) w = W_lin[(size_t)l * FI * FI + k * FI + f];
      Blin[i] = f2bfu(w);
    }
  }
}

// mega3 (256 thr): fill | scalers
__global__ __launch_bounds__(256) void k_mega3(
    const int* __restrict__ srcp, const int* __restrict__ dstp,
    const int* __restrict__ attr, int* __restrict__ cur, int2* __restrict__ csr,
    const int* __restrict__ deg, const float* __restrict__ avglog,
    float* __restrict__ amp, float* __restrict__ att, float* __restrict__ inv) {
  int b = blockIdx.x, t = threadIdx.x;
  if (b < 1250) {
    int e = b * 256 + t;
    if (e < NE) {
      int pos = atomicAdd(&cur[dstp[e]], 1);
      csr[pos] = make_int2(srcp[e], attr[e]);
    }
  } else {
    int i = (b - 1250) * 256 + t;
    if (i < NN) {
      float dc = fmaxf((float)deg[i], 1.f);
      float ld = logf(dc + 1.f);
      float av = avglog[0];
      amp[i] = ld / av;
      att[i] = av / ld;
      inv[i] = 1.f / dc;
    }
  }
}

// ================= per-layer =================
// prepx: xh (self rows for phase2) + xq (bf16 x rows, 80-wide) + zero bnsum.
__global__ __launch_bounds__(256) void k_prepx(const float* __restrict__ x,
                                               const int* __restrict__ deg,
                                               unsigned short* __restrict__ xh,
                                               unsigned short* __restrict__ xq,
                                               float* __restrict__ bnsum) {
  int tid = threadIdx.x;
  if (blockIdx.x == 0 && tid < 150) bnsum[tid] = 0.f;
  for (int i = blockIdx.x * 256 + tid; i < NN * 160; i += 625 * 256) {
    int r = i / 160, k = i - r * 160;
    float v = 0.f;
    if (k < FI) v = x[(size_t)r * FI + k] * ((deg[r] > 0) ? 1.f : 0.f);
    else if (k < 150) v = x[(size_t)r * FI + k - FI];
    xh[i] = f2bfu(v);
  }
  for (int i = blockIdx.x * 256 + tid; i < NN * 80; i += 625 * 256) {
    int r = i / 80, k = i - r * 80;
    xq[i] = (k < FI) ? f2bfu(x[(size_t)r * FI + k]) : 0;
  }
}

// fused aggregate+post: block = 1024 thr = 16 nodes, one node per 32-edge round.
// phase1 v8 (repairs R7's measured pathologies):
//  - K=160 A rows [x_src|pad|te[attr]|pad]: edge term in the MFMA, bias b_pre[col]
//    as a per-lane constant -> NO per-edge table reads (R7: 10.5M bank conflicts).
//  - 32 edges per barrier round (2 sub-tiles; block-uniform skip of sub-tile 2).
//  - waves 12..15 = pure stagers (csr prefetched 1 round ahead, xq/tq -> A buf
//    double-buffered); waves 0..11 compute, 2 column-tiles each, B in registers.
// phase2: waves 0..4 = towers, A from sm + xh, 15 kb MFMAs x3 -> z bf16 LDS.
// phase3: waves 0..4: y cols = z@W_lin + bc -> global + BN partials.
__global__ __launch_bounds__(1024) void k_aggpost(
    const unsigned short* __restrict__ xq, const unsigned short* __restrict__ tqL,
    const int2* __restrict__ csr, const int* __restrict__ off,
    const float* __restrict__ inv_deg, const unsigned short* __restrict__ xh,
    const unsigned short* __restrict__ Bp, const float* __restrict__ amp,
    const float* __restrict__ att, const unsigned short* __restrict__ BlinL,
    const float* __restrict__ bcL, const float* __restrict__ bpreL,
    float* __restrict__ yout, float* __restrict__ bnsum,
    const unsigned short* __restrict__ Bx2L) {
  __shared__ __align__(16) unsigned short sm[16 * SMS];      // 50.3 KB
  __shared__ __align__(16) unsigned short Ab[2][32 * 168];   // 21 KB A dbuf
  __shared__ __align__(16) unsigned short zs[16 * 96];       // 3 KB
  __shared__ int offL[17];
  __shared__ int cumR[17];
  __shared__ float ysum[FI], ysq[FI];
  int tid = threadIdx.x;
  int wv = tid >> 6, lane = tid & 63;
  int m16 = lane & 15, quad = lane >> 4;
  int rel0 = blockIdx.x * 16;
  if (tid < 17) offL[tid] = off[rel0 + tid];
  if (tid < FI) { ysum[tid] = 0.f; ysq[tid] = 0.f; }
  for (int idx = tid; idx < 1600; idx += 1024) {   // zero per-tower pads
    int h = idx / 100, pp = idx - h * 100;
    int t = pp / 20, cc = pp - t * 20;
    sm[h * SMS + t * 320 + 300 + cc] = 0;
  }
  for (int i = tid; i < 16 * 21; i += 1024) {      // zero zs k-pad cols 75..95
    int r = i / 21, k = 75 + i - r * 21;
    zs[r * 96 + k] = 0;
  }
  __syncthreads();
  if (tid == 0) {
    int a = 0;
#pragma unroll
    for (int i = 0; i < 16; ++i) {
      cumR[i] = a;
      a += (offL[i + 1] - offL[i] + 31) >> 5;
    }
    cumR[16] = a;
  }
  // compute-wave setup: 2 column tiles, B frags in regs, bias consts
  int nt0 = 2 * wv;                     // valid for wv<12
  int col0 = nt0 * 16 + m16, col1 = col0 + 16;
  v8s B00, B01, B02, B03, B04, B10, B11, B12, B13, B14;
  float cb0 = 0.f, cb1 = 0.f;
  float s0 = 0.f, q0 = 0.f, mn0 = INFINITY, mx0 = -INFINITY;
  float s1 = 0.f, q1 = 0.f, mn1 = INFINITY, mx1 = -INFINITY;
  if (wv < 12) {
    B00 = *(const v8s*)(Bx2L + ((size_t)(0 * 24 + nt0) * 64 + lane) * 8);
    B01 = *(const v8s*)(Bx2L + ((size_t)(1 * 24 + nt0) * 64 + lane) * 8);
    B02 = *(const v8s*)(Bx2L + ((size_t)(2 * 24 + nt0) * 64 + lane) * 8);
    B03 = *(const v8s*)(Bx2L + ((size_t)(3 * 24 + nt0) * 64 + lane) * 8);
    B04 = *(const v8s*)(Bx2L + ((size_t)(4 * 24 + nt0) * 64 + lane) * 8);
    B10 = *(const v8s*)(Bx2L + ((size_t)(0 * 24 + nt0 + 1) * 64 + lane) * 8);
    B11 = *(const v8s*)(Bx2L + ((size_t)(1 * 24 + nt0 + 1) * 64 + lane) * 8);
    B12 = *(const v8s*)(Bx2L + ((size_t)(2 * 24 + nt0 + 1) * 64 + lane) * 8);
    B13 = *(const v8s*)(Bx2L + ((size_t)(3 * 24 + nt0 + 1) * 64 + lane) * 8);
    B14 = *(const v8s*)(Bx2L + ((size_t)(4 * 24 + nt0 + 1) * 64 + lane) * 8);
    if (col0 < CH) cb0 = bpreL[col0];
    if (col1 < CH) cb1 = bpreL[col1];
    // empty-node prepass
    float sd0 = sqrtf(1e-5f);
    for (int i = 0; i < 16; ++i) {
      if (offL[i + 1] == offL[i] && quad == 0) {
#pragma unroll
        for (int h = 0; h < 2; ++h) {
          int col = h ? col1 : col0;
          if (col < CH) {
            int tc = col / 75, ch = col - tc * 75;
            unsigned short* bb = sm + i * SMS + tc * 320;
            bb[ch] = 0; bb[75 + ch] = 0; bb[150 + ch] = 0; bb[225 + ch] = f2bfu(sd0);
          }
        }
      }
    }
  }
  __syncthreads();
  int R = cumR[16];
  // stager state (waves 12..15)
  int t2 = tid - 768;
  int E0 = t2 / 20, C0 = t2 - E0 * 20;
  int E1 = (t2 + 256) / 20, C1 = (t2 + 256) - E1 * 20;
  int E2 = (t2 + 512) / 20, C2 = (t2 + 512) - E2 * 20;
  int2 cs0 = make_int2(0, 0), cs1 = cs0, cs2 = cs0;
  int siS = 0;
  const uint4* xq4 = (const uint4*)xq;
  const uint4* tq4 = (const uint4*)tqL;
  uint4* Ab4 = (uint4*)Ab;
  auto prefetchCsr = [&](int Y) {
    while (Y >= cumR[siS + 1]) ++siS;
    int bs = offL[siS] + (Y - cumR[siS]) * 32;
    int om = offL[siS + 1] - 1;
    int e0 = bs + E0; if (e0 > om) e0 = om;
    int e1 = bs + E1; if (e1 > om) e1 = om;
    cs0 = csr[e0];
    cs1 = csr[e1];
    if (t2 < 128) { int e2 = bs + E2; if (e2 > om) e2 = om; cs2 = csr[e2]; }
  };
  auto stageWrite = [&](int X) {
    uint4* dst = Ab4 + (X & 1) * 672;
    dst[E0 * 21 + C0] = (C0 < 10) ? xq4[(size_t)cs0.x * 10 + C0]
                                  : tq4[(size_t)cs0.y * 10 + (C0 - 10)];
    dst[E1 * 21 + C1] = (C1 < 10) ? xq4[(size_t)cs1.x * 10 + C1]
                                  : tq4[(size_t)cs1.y * 10 + (C1 - 10)];
    if (t2 < 128)
      dst[E2 * 21 + C2] = (C2 < 10) ? xq4[(size_t)cs2.x * 10 + C2]
                                    : tq4[(size_t)cs2.y * 10 + (C2 - 10)];
  };
  auto subtile = [&](const unsigned short* A, int base, int o1m1) {
    const unsigned short* ar = A + m16 * 168 + quad * 8;
    v8s a0 = *(const v8s*)(ar);
    v8s a1 = *(const v8s*)(ar + 32);
    v8s a2 = *(const v8s*)(ar + 64);
    v8s a3 = *(const v8s*)(ar + 96);
    v8s a4 = *(const v8s*)(ar + 128);
    v4f p0 = {0.f, 0.f, 0.f, 0.f}, p1 = p0;
    p0 = __builtin_amdgcn_mfma_f32_16x16x32_bf16(a0, B00, p0, 0, 0, 0);
    p0 = __builtin_amdgcn_mfma_f32_16x16x32_bf16(a1, B01, p0, 0, 0, 0);
    p0 = __builtin_amdgcn_mfma_f32_16x16x32_bf16(a2, B02, p0, 0, 0, 0);
    p0 = __builtin_amdgcn_mfma_f32_16x16x32_bf16(a3, B03, p0, 0, 0, 0);
    p0 = __builtin_amdgcn_mfma_f32_16x16x32_bf16(a4, B04, p0, 0, 0, 0);
    p1 = __builtin_amdgcn_mfma_f32_16x16x32_bf16(a0, B10, p1, 0, 0, 0);
    p1 = __builtin_amdgcn_mfma_f32_16x16x32_bf16(a1, B11, p1, 0, 0, 0);
    p1 = __builtin_amdgcn_mfma_f32_16x16x32_bf16(a2, B12, p1, 0, 0, 0);
    p1 = __builtin_amdgcn_mfma_f32_16x16x32_bf16(a3, B13, p1, 0, 0, 0);
    p1 = __builtin_amdgcn_mfma_f32_16x16x32_bf16(a4, B14, p1, 0, 0, 0);
    int er = base + quad * 4;
#pragma unroll
    for (int j = 0; j < 4; ++j) {
      bool v = (er + j) <= o1m1;
      float z = p0[j] + cb0;
      s0 = v ? s0 + z : s0;
      q0 = v ? fmaf(z, z, q0) : q0;
      mn0 = v ? fminf(mn0, z) : mn0;
      mx0 = v ? fmaxf(mx0, z) : mx0;
      float w = p1[j] + cb1;
      s1 = v ? s1 + w : s1;
      q1 = v ? fmaf(w, w, q1) : q1;
      mn1 = v ? fminf(mn1, w) : mn1;
      mx1 = v ? fmaxf(mx1, w) : mx1;
    }
  };
  // prologue
  if (wv >= 12 && R > 0) {
    prefetchCsr(0);
    stageWrite(0);
    if (R > 1) prefetchCsr(1);
  }
  __syncthreads();
  int ci = 0;
  for (int r = 0; r < R; ++r) {
    if (wv >= 12) {
      if (r + 1 < R) stageWrite(r + 1);
      if (r + 2 < R) prefetchCsr(r + 2);
    } else {
      while (r >= cumR[ci + 1]) ++ci;
      int o0i = offL[ci], o1i = offL[ci + 1];
      int base = o0i + (r - cumR[ci]) * 32;
      const unsigned short* A = (const unsigned short*)Ab + (r & 1) * (32 * 168);
      int o1m1 = o1i - 1;
      subtile(A, base, o1m1);
      if (base + 16 < o1i) subtile(A + 16 * 168, base + 16, o1m1);
      if (r == cumR[ci + 1] - 1) {        // node end: reduce + write sm
        float inv = inv_deg[rel0 + ci];
#pragma unroll
        for (int h = 0; h < 2; ++h) {
          float S = h ? s1 : s0, Q = h ? q1 : q0;
          float MN = h ? mn1 : mn0, MX = h ? mx1 : mx0;
          S += __shfl_xor(S, 16); S += __shfl_xor(S, 32);
          Q += __shfl_xor(Q, 16); Q += __shfl_xor(Q, 32);
          MN = fminf(MN, __shfl_xor(MN, 16)); MN = fminf(MN, __shfl_xor(MN, 32));
          MX = fmaxf(MX, __shfl_xor(MX, 16)); MX = fmaxf(MX, __shfl_xor(MX, 32));
          if (quad == 0) {
            int col = h ? col1 : col0;
            if (col < CH) {
              float me = S * inv;
              float sd = sqrtf(fmaxf(Q * inv - me * me, 0.f) + 1e-5f);
              int tc = col / 75, ch = col - tc * 75;
              unsigned short* bb = sm + ci * SMS + tc * 320;
              bb[ch] = f2bfu(me);
              bb[75 + ch] = f2bfu(MN);
              bb[150 + ch] = f2bfu(MX);
              bb[225 + ch] = f2bfu(sd);
            }
          }
        }
        s0 = 0.f; q0 = 0.f; mn0 = INFINITY; mx0 = -INFINITY;
        s1 = 0.f; q1 = 0.f; mn1 = INFINITY; mx1 = -INFINITY;
      }
    }
    __syncthreads();
  }
  __syncthreads();
  // ---- phase 2: tower MFMA from LDS ----
  if (wv < NT) {
    int tw = wv;
    const unsigned short* arow = sm + m16 * SMS + tw * 320 + quad * 8;
    const unsigned short* xrow = xh + (size_t)(rel0 + m16) * 160 + quad * 8;
    const unsigned short* bp = Bp + ((size_t)tw * 3 * 15 * 64) * 8 + lane * 8;
    v4f a0 = {0.f, 0.f, 0.f, 0.f}, a1 = a0, a2 = a0;
#pragma unroll
    for (int kb = 0; kb < 15; ++kb) {
      v8s av = *(const v8s*)((kb < 10) ? (arow + kb * 32) : (xrow + (kb - 10) * 32));
      const unsigned short* bb = bp + (size_t)kb * 512;
      v8s b0 = *(const v8s*)(bb);
      v8s b1 = *(const v8s*)(bb + 15 * 512);
      v8s b2 = *(const v8s*)(bb + 30 * 512);
      a0 = __builtin_amdgcn_mfma_f32_16x16x32_bf16(av, b0, a0, 0, 0, 0);
      a1 = __builtin_amdgcn_mfma_f32_16x16x32_bf16(av, b1, a1, 0, 0, 0);
      a2 = __builtin_amdgcn_mfma_f32_16x16x32_bf16(av, b2, a2, 0, 0, 0);
    }
    int f = m16;
    if (f < FO) {
      int relZ = quad * 4;
#pragma unroll
      for (int r = 0; r < 4; ++r) {
        int nd = rel0 + relZ + r;
        int ndc = (nd < NN) ? nd : (NN - 1);
        float zz = a0[r] + amp[ndc] * a1[r] + att[ndc] * a2[r];
        zs[(relZ + r) * 96 + tw * FO + f] = f2bfu(zz);
      }
    }
  }
  __syncthreads();
  // ---- phase 3: y cols [tw*16, tw*16+16) ----
  if (wv < NT) {
    int tw = wv;
    v4f acc2 = {0.f, 0.f, 0.f, 0.f};
#pragma unroll
    for (int kb = 0; kb < 3; ++kb) {
      v8s av = *(const v8s*)(zs + m16 * 96 + quad * 8 + kb * 32);
      v8s bl = *(const v8s*)(BlinL + ((size_t)(kb * 5 + tw) * 64 + lane) * 8);
      acc2 = __builtin_amdgcn_mfma_f32_16x16x32_bf16(av, bl, acc2, 0, 0, 0);
    }
    int fcol = tw * 16 + m16;
    if (fcol < FI) {
      float bcf = bcL[fcol];
      int nb = rel0 + quad * 4;
#pragma unroll
      for (int r = 0; r < 4; ++r) {
        int nd = nb + r;
        if (nd < NN) {
          float v = acc2[r] + bcf;
          yout[(size_t)nd * FI + fcol] = v;
          atomicAdd(&ysum[fcol], v);
          atomicAdd(&ysq[fcol], v * v);
        }
      }
    }
  }
  __syncthreads();
  if (tid < FI) {
    atomicAdd(&bnsum[tid], ysum[tid]);
    atomicAdd(&bnsum[FI + tid], ysq[tid]);
  }
}

// BN finalize+apply; dopool==0: also zero pooled for next layer; dopool==1: pool.
__global__ __launch_bounds__(256) void k_bnfinapply(const float* __restrict__ y,
    const float* __restrict__ bnsum, const float* __restrict__ gamL,
    const float* __restrict__ betL, float* __restrict__ xo,
    const int* __restrict__ batch, float* __restrict__ pooled, int dopool) {
  __shared__ float sc[150];
  int tid = threadIdx.x;
  if (tid < FI) {
    float mu = bnsum[tid] / (float)NN;
    float var = bnsum[FI + tid] / (float)NN - mu * mu;
    float scl = gamL[tid] * rsqrtf(var + 1e-5f);
    sc[tid] = scl;
    sc[FI + tid] = betL[tid] - mu * scl;
  }
  if (!dopool) {
    for (int i = blockIdx.x * 256 + tid; i < NG * FI; i += gridDim.x * 256)
      pooled[i] = 0.f;
  }
  __syncthreads();
  int stride = gridDim.x * 256;
  for (int i = blockIdx.x * 256 + tid; i < NN * FI; i += stride) {
    int n = i / FI, f = i - n * FI;
    float v = fmaxf(fmaf(y[i], sc[f], sc[FI + f]), 0.f);
    xo[i] = v;
    if (dopool) atomicAdd(&pooled[batch[n] * FI + f], v);
  }
}

__global__ void k_head(const float* __restrict__ pooled, const float* __restrict__ W1,
                       const float* __restrict__ b1, const float* __restrict__ W2,
                       const float* __restrict__ b2, const float* __restrict__ W3,
                       const float* __restrict__ b3, float* __restrict__ out) {
  __shared__ float p[FI], h1[50], h2[25];
  int g = blockIdx.x, t = threadIdx.x;
  for (int i = t; i < FI; i += 64) p[i] = pooled[g * FI + i];
  __syncthreads();
  if (t < 50) {
    float a = b1[t];
    for (int j = 0; j < FI; ++j) a = fmaf(p[j], W1[j * 50 + t], a);
    h1[t] = fmaxf(a, 0.f);
  }
  __syncthreads();
  if (t < 25) {
    float a = b2[t];
    for (int j = 0; j < 50; ++j) a = fmaf(h1[j], W2[j * 25 + t], a);
    h2[t] = fmaxf(a, 0.f);
  }
  __syncthreads();
  if (t == 0) {
    float a = b3[0];
    for (int j = 0; j < 25; ++j) a = fmaf(h2[j], W3[j], a);
    out[g] = a;
  }
}

extern "C" void kernel_launch(void* const* d_in, const int* in_sizes, int n_in,
                              void* d_out, int out_size, void* d_ws, size_t ws_size,
                              hipStream_t stream) {
  const int* x_idx = (const int*)d_in[0];
  const int* eidx  = (const int*)d_in[1];
  const int* srcp  = eidx;
  const int* dstp  = eidx + NE;
  const int* eattr = (const int*)d_in[2];
  const int* batch = (const int*)d_in[3];
  const float* node_emb = (const float*)d_in[4];
  const float* edge_emb = (const float*)d_in[5];
  const float* W_edge = (const float*)d_in[6];
  const float* b_edge = (const float*)d_in[7];
  const float* W_pre  = (const float*)d_in[8];
  const float* b_pre  = (const float*)d_in[9];
  const float* W_post = (const float*)d_in[10];
  const float* b_post = (const float*)d_in[11];
  const float* W_lin  = (const float*)d_in[12];
  const float* b_lin  = (const float*)d_in[13];
  const float* gam = (const float*)d_in[14];
  const float* bet = (const float*)d_in[15];
  const float* W1 = (const float*)d_in[16];
  const float* b1 = (const float*)d_in[17];
  const float* W2 = (const float*)d_in[18];
  const float* b2 = (const float*)d_in[19];
  const float* W3 = (const float*)d_in[20];
  const float* b3 = (const float*)d_in[21];

  char* p = (char*)d_ws;
  auto alloc = [&](size_t b) -> char* {
    char* r = p;
    p += (b + 255) & ~(size_t)255;
    return r;
  };
  float* x_a   = (float*)alloc((size_t)NN * FI * 4);
  float* x_b   = (float*)alloc((size_t)NN * FI * 4);
  unsigned short* xq = (unsigned short*)alloc((size_t)NN * 80 * 2);
  float* z     = (float*)alloc((size_t)NN * FI * 4);
  unsigned short* xh = (unsigned short*)alloc((size_t)(NN + 64) * 160 * 2);
  float* te    = (float*)alloc(2 * 100 * FI * 4);
  unsigned short* tq = (unsigned short*)alloc((size_t)2 * 100 * 80 * 2);
  float* WAs   = (float*)alloc((size_t)2 * FI * CH * 4);
  float* V     = (float*)alloc((size_t)2 * NT * 3 * FI * 16 * 4);
  unsigned short* Bpk = (unsigned short*)alloc((size_t)230400 * 2);
  unsigned short* Bx2 = (unsigned short*)alloc((size_t)122880 * 2);
  unsigned short* Blin = (unsigned short*)alloc((size_t)15360 * 2);
  float* bc    = (float*)alloc(2 * 76 * 4);
  float* ampv  = (float*)alloc((size_t)NN * 4);
  float* attv  = (float*)alloc((size_t)NN * 4);
  float* invv  = (float*)alloc((size_t)NN * 4);
  float* avglog = (float*)alloc(256);
  float* bnsum = (float*)alloc(2 * FI * 4);
  float* pooled = (float*)alloc((size_t)NG * FI * 4);
  int* deg = (int*)alloc((size_t)NN * 4);
  int* off = (int*)alloc((size_t)(NN + 1) * 4);
  int* cur = (int*)alloc((size_t)NN * 4);
  int2* csr = (int2*)alloc((size_t)NE * 8);

  hipMemsetAsync(deg, 0, (size_t)NN * 4, stream);

  k_mega1<<<7562, 256, 0, stream>>>(x_idx, node_emb, x_a, dstp, deg,
                                    edge_emb, W_edge, b_edge, te,
                                    W_pre, WAs, W_post, V,
                                    b_post, W_lin, b_lin, bc);
  k_mega2<<<378, 1024, 0, stream>>>(deg, off, cur, avglog,
                                    te, tq, W_pre, W_post, V, Bpk,
                                    WAs, Bx2, W_lin, Blin);
  k_mega3<<<1329, 256, 0, stream>>>(srcp, dstp, eattr, cur, csr,
                                    deg, avglog, ampv, attv, invv);

  for (int l = 0; l < 2; ++l) {
    const float* xin = (l == 0) ? x_a : x_b;
    float* xout = (l == 0) ? x_b : x_a;
    k_prepx<<<625, 256, 0, stream>>>(xin, deg, xh, xq, bnsum);
    k_aggpost<<<1250, 1024, 0, stream>>>(xq, tq + (size_t)l * 8000, csr, off, invv,
                                         xh, Bpk + (size_t)l * 115200, ampv, attv,
                                         Blin + (size_t)l * 7680, bc + l * 76,
                                         b_pre + (size_t)l * CH,
                                         z, bnsum, Bx2 + (size_t)l * 61440);
    k_bnfinapply<<<1250, 256, 0, stream>>>(z, bnsum, gam + l * FI, bet + l * FI,
                                           xout, batch, pooled, (l == 1) ? 1 : 0);
  }

  k_head<<<NG, 64, 0, stream>>>(pooled, W1, b1, W2, b2, W3, b3, (float*)d_out);
}

// Round 9
// 424.583 us; speedup vs baseline: 1.7279x; 1.6002x over previous
//
#include <hip/hip_runtime.h>
#include <hip/hip_bf16.h>
#include <math.h>

#define NN 20000
#define NE 320000
#define NG 200
#define FI 75
#define NT 5
#define FO 15
#define CH 375     // NT*FI
#define PI 975
#define SMS 1608   // LDS stats row stride (ushorts): 16B-aligned, 2-way-free banks

typedef __attribute__((ext_vector_type(8))) short v8s;
typedef __attribute__((ext_vector_type(4))) float v4f;

__device__ __forceinline__ unsigned short f2bfu(float v) {
  __hip_bfloat16 h = __float2bfloat16(v);
  return *reinterpret_cast<unsigned short*>(&h);
}
__device__ __forceinline__ float uif(unsigned u) { return __uint_as_float(u); }

// ================= prep mega kernels =================
// mega1 (256 thr): gather_x | count | table_e | repack_WAs | make_V | bias_comb
__global__ __launch_bounds__(256) void k_mega1(
    const int* __restrict__ xidx, const float* __restrict__ emb, float* __restrict__ x,
    const int* __restrict__ dstp, int* __restrict__ deg,
    const float* __restrict__ eemb, const float* __restrict__ W_edge,
    const float* __restrict__ b_edge, float* __restrict__ te,
    const float* __restrict__ W_pre, float* __restrict__ WAs,
    const float* __restrict__ W_post, float* __restrict__ V,
    const float* __restrict__ b_post, const float* __restrict__ W_lin,
    const float* __restrict__ b_lin, float* __restrict__ bc) {
  __shared__ float S[FI * 16];
  int b = blockIdx.x, tid = threadIdx.x;
  if (b < 5860) {                       // gather_x
    int i = b * 256 + tid;
    if (i < NN * FI) {
      int n = i / FI, f = i - n * FI;
      x[i] = emb[xidx[n] * FI + f];
    }
  } else if (b < 7110) {                // count
    int e = (b - 5860) * 256 + tid;
    if (e < NE) atomicAdd(&deg[dstp[e]], 1);
  } else if (b < 7310) {                // table_e
    int la = b - 7110;
    int l = la / 100, a = la - l * 100;
    int f = tid;
    if (f < FI) {
      float acc = b_edge[l * FI + f];
      for (int j = 0; j < 50; ++j)
        acc = fmaf(eemb[a * 50 + j], W_edge[(l * 50 + j) * FI + f], acc);
      te[la * FI + f] = acc;
    }
  } else if (b < 7530) {                // repack_WAs
    int i = (b - 7310) * 256 + tid;
    if (i < 2 * FI * CH) {
      int c = i % CH;
      int k = (i / CH) % FI;
      int l = i / (CH * FI);
      int t = c / FI, f = c - t * FI;
      WAs[i] = W_pre[((size_t)(l * NT + t) * 225 + FI + k) * FI + f];
    }
  } else if (b < 7560) {                // make_V
    int bid = b - 7530;                 // (l*5+t)*3+g
    int g = bid % 3;
    int lt = bid / 3;
    for (int idx = tid; idx < FI * 16; idx += 256) {
      int q = idx >> 4, f = idx & 15;
      float v = 0.f;
      if (f < FO) {
        const float* wb = W_post + (size_t)lt * PI * FO;
        int rowb = FI + g * 300 + q;
        v = wb[rowb * FO + f] + wb[(rowb + FI) * FO + f] + wb[(rowb + 2 * FI) * FO + f];
      }
      S[idx] = v;
    }
    __syncthreads();
    for (int idx = tid; idx < FI * 16; idx += 256) {
      int j = idx >> 4, f = idx & 15;
      float acc = 0.f;
      const float* wr = W_pre + ((size_t)lt * 225 + j) * FI;
      for (int q = 0; q < FI; ++q) acc = fmaf(wr[q], S[q * 16 + f], acc);
      V[((size_t)bid * FI + j) * 16 + f] = acc;
    }
  } else {                              // bias_comb
    int l = b - 7560;
    int g = tid;
    if (g < FI) {
      float acc = b_lin[l * FI + g];
      for (int j = 0; j < FI; ++j)
        acc = fmaf(b_post[l * FI + j], W_lin[(l * FI + j) * FI + g], acc);
      bc[l * 76 + g] = acc;
    }
  }
}

// mega2 (1024 thr): scan | logsum | tbl_m | pack_B | pack_Bxs | pack_Blin
__global__ __launch_bounds__(1024) void k_mega2(
    const int* __restrict__ deg, int* __restrict__ off, int* __restrict__ cur,
    float* __restrict__ avglog,
    const float* __restrict__ te, const float* __restrict__ W_pre,
    const float* __restrict__ b_pre, unsigned short* __restrict__ tm,
    const float* __restrict__ W_post, const float* __restrict__ V,
    unsigned short* __restrict__ Bp,
    const float* __restrict__ WAs, unsigned short* __restrict__ Bxs,
    const float* __restrict__ W_lin, unsigned short* __restrict__ Blin) {
  __shared__ float red[1024];
  int b = blockIdx.x, t = threadIdx.x;
  if (b == 0) {                         // scan: 1024 x 20
    int* wsum = (int*)red;
    int base = t * 20;
    int loc[20];
    int s = 0;
#pragma unroll
    for (int j = 0; j < 20; ++j) {
      int i = base + j;
      int v = (i < NN) ? deg[i] : 0;
      loc[j] = s;
      s += v;
    }
    int lane = t & 63, w = t >> 6;
    int inc = s;
    for (int o = 1; o < 64; o <<= 1) {
      int u = __shfl_up(inc, o, 64);
      if (lane >= o) inc += u;
    }
    if (lane == 63) wsum[w] = inc;
    __syncthreads();
    if (t == 0) {
      int a = 0;
#pragma unroll
      for (int k = 0; k < 16; ++k) { int v = wsum[k]; wsum[k] = a; a += v; }
    }
    __syncthreads();
    int tex = wsum[w] + inc - s;
#pragma unroll
    for (int j = 0; j < 20; ++j) {
      int i = base + j;
      if (i < NN) { int e = tex + loc[j]; off[i] = e; cur[i] = e; }
    }
    if (t == 1023) off[NN] = tex + s;
  } else if (b == 1) {                  // logsum
    float s = 0.f;
    for (int i = t; i < NN; i += 1024) s += logf((float)deg[i] + 1.f);
    red[t] = s;
    __syncthreads();
    for (int o = 512; o > 0; o >>= 1) {
      if (t < o) red[t] += red[t + o];
      __syncthreads();
    }
    if (t == 0) avglog[0] = red[0] / (float)NN;
  } else if (b < 77) {                  // tbl_m flat: 2*100*384
    int idx = (b - 2) * 1024 + t;
    if (idx < 76800) {
      int la = idx / 384, c = idx - la * 384;
      int l = la / 100;
      float acc = 0.f;
      if (c < CH) {
        int tt = c / FI, f = c - tt * FI;
        acc = b_pre[(l * NT + tt) * FI + f];
        const float* ter = te + la * FI;
        for (int k = 0; k < FI; ++k)
          acc = fmaf(ter[k], W_pre[((size_t)(l * NT + tt) * 225 + 150 + k) * FI + f], acc);
      }
      tm[(size_t)la * 384 + c] = f2bfu(acc);
    }
  } else if (b < 302) {                 // pack_B (post MFMA weights)
    int i = (b - 77) * 1024 + t;
    if (i < 230400) {
      int j = i & 7;
      int lane = (i >> 3) & 63;
      int rem = i >> 9;
      int kb = rem % 15; rem /= 15;
      int g = rem % 3; rem /= 3;
      int tt = rem % 5;
      int l = rem / 5;
      int k = kb * 32 + (lane >> 4) * 8 + j;
      int f = lane & 15;
      float w = 0.f;
      if (f < FO) {
        int lt = l * NT + tt;
        if (k < 300) {
          int a = k / 75, ch = k - a * 75;
          w = W_post[((size_t)lt * PI + FI + g * 300 + a * 75 + ch) * FO + f];
        } else if (k >= 320 && k < 395) {
          w = V[(((size_t)(lt * 3 + g)) * FI + (k - 320)) * 16 + f];
        } else if (k >= 395 && k < 470 && g == 0) {
          w = W_post[((size_t)lt * PI + (k - 395)) * FO + f];
        }
      }
      Bp[i] = f2bfu(w);
    }
  } else if (b < 374) {                 // pack_Bxs (xs MFMA weights), 73728 elems
    int i = (b - 302) * 1024 + t;
    if (i < 73728) {
      int j = i & 7;
      int lane = (i >> 3) & 63;
      int rem = i >> 9;                 // 0..143
      int nt = rem % 24; rem /= 24;
      int kb = rem % 3;
      int l = rem / 3;
      int k = kb * 32 + (lane >> 4) * 8 + j;
      int n = nt * 16 + (lane & 15);
      float w = 0.f;
      if (k < FI && n < CH) w = WAs[(size_t)l * FI * CH + k * CH + n];
      Bxs[i] = f2bfu(w);
    }
  } else {                              // pack_Blin (W_lin MFMA weights), 15360 elems
    int i = (b - 374) * 1024 + t;
    if (i < 15360) {
      int j = i & 7;
      int lane = (i >> 3) & 63;
      int rem = i >> 9;                 // 0..29
      int nt = rem % 5; rem /= 5;
      int kb = rem % 3;
      int l = rem / 3;
      int k = kb * 32 + (lane >> 4) * 8 + j;
      int f = nt * 16 + (lane & 15);
      float w = 0.f;
      if (k < FI && f < FI) w = W_lin[(size_t)l * FI * FI + k * FI + f];
      Blin[i] = f2bfu(w);
    }
  }
}

// mega3 (256 thr): fill | scalers | zero bnsum ping-pong
__global__ __launch_bounds__(256) void k_mega3(
    const int* __restrict__ srcp, const int* __restrict__ dstp,
    const int* __restrict__ attr, int* __restrict__ cur, int2* __restrict__ csr,
    const int* __restrict__ deg, const float* __restrict__ avglog,
    float* __restrict__ amp, float* __restrict__ att, float* __restrict__ inv,
    float* __restrict__ bnsumA, float* __restrict__ bnsumB) {
  int b = blockIdx.x, t = threadIdx.x;
  if (b < 1250) {
    int e = b * 256 + t;
    if (e < NE) {
      int pos = atomicAdd(&cur[dstp[e]], 1);
      csr[pos] = make_int2(srcp[e], attr[e]);
    }
  } else if (b < 1329) {
    int i = (b - 1250) * 256 + t;
    if (i < NN) {
      float dc = fmaxf((float)deg[i], 1.f);
      float ld = logf(dc + 1.f);
      float av = avglog[0];
      amp[i] = ld / av;
      att[i] = av / ld;
      inv[i] = 1.f / dc;
    }
  } else {
    if (t < 150) { bnsumA[t] = 0.f; bnsumB[t] = 0.f; }
  }
}

// ================= per-layer =================
// y==0: xs_bf[n,0:384] = x@W_pre_src via MFMA.  y==1 (layer 0 only): build xh.
__global__ __launch_bounds__(256) void k_gemm_xs(const float* __restrict__ x,
                                                 const unsigned short* __restrict__ BxsL,
                                                 unsigned short* __restrict__ xsb,
                                                 const int* __restrict__ deg,
                                                 unsigned short* __restrict__ xh) {
  int tid = threadIdx.x;
  if (blockIdx.y == 1) {
    for (int i = blockIdx.x * 256 + tid; i < NN * 160; i += 625 * 256) {
      int r = i / 160, k = i - r * 160;
      float v = 0.f;
      if (k < FI) v = x[(size_t)r * FI + k] * ((deg[r] > 0) ? 1.f : 0.f);
      else if (k < 150) v = x[(size_t)r * FI + k - FI];
      xh[i] = f2bfu(v);
    }
    return;
  }
  __shared__ unsigned short As[32 * 104];   // K padded to 96, stride 104
  __shared__ unsigned short Os[32 * 384];
  int m0 = blockIdx.x * 32;
  for (int i = tid; i < 32 * 104; i += 256) {
    int r = i / 104, k = i - r * 104;
    As[i] = (k < FI) ? f2bfu(x[(size_t)(m0 + r) * FI + k]) : 0;
  }
  __syncthreads();
  int lane = tid & 63, w = tid >> 6;        // wave w: n-cols [w*96, w*96+96)
  int m16 = lane & 15, quad = lane >> 4;
  v4f acc0[6], acc1[6];
#pragma unroll
  for (int nt = 0; nt < 6; ++nt) {
    acc0[nt] = {0.f, 0.f, 0.f, 0.f};
    acc1[nt] = {0.f, 0.f, 0.f, 0.f};
  }
  const unsigned short* arow0 = As + m16 * 104 + quad * 8;
  const unsigned short* arow1 = As + (16 + m16) * 104 + quad * 8;
#pragma unroll
  for (int kb = 0; kb < 3; ++kb) {
    v8s a0 = *(const v8s*)(arow0 + kb * 32);
    v8s a1 = *(const v8s*)(arow1 + kb * 32);
#pragma unroll
    for (int nt = 0; nt < 6; ++nt) {
      v8s bf = *(const v8s*)(BxsL + ((size_t)(kb * 24 + w * 6 + nt) * 64 + lane) * 8);
      acc0[nt] = __builtin_amdgcn_mfma_f32_16x16x32_bf16(a0, bf, acc0[nt], 0, 0, 0);
      acc1[nt] = __builtin_amdgcn_mfma_f32_16x16x32_bf16(a1, bf, acc1[nt], 0, 0, 0);
    }
  }
#pragma unroll
  for (int nt = 0; nt < 6; ++nt) {
    int col = w * 96 + nt * 16 + m16;
#pragma unroll
    for (int r = 0; r < 4; ++r) {
      Os[(quad * 4 + r) * 384 + col] = f2bfu(acc0[nt][r]);
      Os[(16 + quad * 4 + r) * 384 + col] = f2bfu(acc1[nt][r]);
    }
  }
  __syncthreads();
  uint4* dst = (uint4*)(xsb + (size_t)m0 * 384);
  const uint4* src = (const uint4*)Os;
  for (int i = tid; i < 1536; i += 256) dst[i] = src[i];
}

// fused aggregate+post: block = 1024 thr (16 waves) = 16 nodes.
// phase1 (pipelined): wave-cooperative csr preload (1 coalesced load / 64 edges),
// per-edge indices pulled to SGPRs via v_readlane -> scalar-base gathers; 4-edge
// double-buffered software pipeline (R2 structure, best measured: 98 us).
// phase2: waves 0..4 = towers, A from LDS, 15 kb MFMAs x3 groups -> z bf16 LDS.
// phase3: waves 0..4: y cols [t*16,t*16+16) = z@W_lin + bc -> global + BN partials.
__global__ __launch_bounds__(1024) void k_aggpost(
    const unsigned short* __restrict__ xs, const int2* __restrict__ csr,
    const int* __restrict__ off, const float* __restrict__ inv_deg,
    const unsigned short* __restrict__ tm, const unsigned short* __restrict__ xh,
    const unsigned short* __restrict__ Bp, const float* __restrict__ amp,
    const float* __restrict__ att, const unsigned short* __restrict__ BlinL,
    const float* __restrict__ bcL, float* __restrict__ yout,
    float* __restrict__ bnsum) {
  __shared__ __align__(16) unsigned short sm[16 * SMS];   // ~50.3 KB
  __shared__ __align__(16) unsigned short zs[16 * 96];    // 3 KB
  __shared__ float ysum[FI], ysq[FI];
  int tid = threadIdx.x;
  int wv = tid >> 6, lane = tid & 63;
  int rel0 = blockIdx.x * 16;
  if (tid < FI) { ysum[tid] = 0.f; ysq[tid] = 0.f; }
  for (int idx = tid; idx < 1600; idx += 1024) {   // zero per-tower pads (16 rows)
    int h = idx / 100, pp = idx - h * 100;
    int t = pp / 20, cc = pp - t * 20;
    sm[h * SMS + t * 320 + 300 + cc] = 0;
  }
  for (int i = tid; i < 16 * 21; i += 1024) {      // zero zs k-pad cols 75..95
    int r = i / 21, k = 75 + i - r * 21;
    zs[r * 96 + k] = 0;
  }
  {
    int n = rel0 + wv;                // 1250*16 == NN: always valid
    int c0 = lane * 6;                // cols 375..383 are zero in xs/tm
    int o0 = off[n], o1 = off[n + 1];
    float s[6], q[6], mn[6], mx[6];
#pragma unroll
    for (int j = 0; j < 6; ++j) {
      s[j] = 0.f; q[j] = 0.f; mn[j] = INFINITY; mx[j] = -INFINITY;
    }
    auto proc = [&](uint3 xv, uint3 tv) {
      unsigned xa[3] = {xv.x, xv.y, xv.z};
      unsigned ta[3] = {tv.x, tv.y, tv.z};
#pragma unroll
      for (int j = 0; j < 3; ++j) {
        float z0 = uif(xa[j] << 16) + uif(ta[j] << 16);
        float z1 = uif(xa[j] & 0xffff0000u) + uif(ta[j] & 0xffff0000u);
        s[2 * j] += z0; q[2 * j] = fmaf(z0, z0, q[2 * j]);
        mn[2 * j] = fminf(mn[2 * j], z0); mx[2 * j] = fmaxf(mx[2 * j], z0);
        s[2 * j + 1] += z1; q[2 * j + 1] = fmaf(z1, z1, q[2 * j + 1]);
        mn[2 * j + 1] = fminf(mn[2 * j + 1], z1); mx[2 * j + 1] = fmaxf(mx[2 * j + 1], z1);
      }
    };
    uint3 xA0, tA0, xA1, tA1, xA2, tA2, xA3, tA3;
    uint3 xB0, tB0, xB1, tB1, xB2, tB2, xB3, tB3;
    for (int base = o0; base < o1; base += 64) {
      int m = o1 - base; if (m > 64) m = 64;
      int ecx = 0, ecy = 0;
      if (base + lane < o1) {
        int2 e = csr[base + lane];     // one coalesced 8B/lane load covers 64 edges
        ecx = e.x; ecy = e.y;
      }
#define LDE(jj, XV, TV) do { \
        int sv_ = __builtin_amdgcn_readlane(ecx, (jj)); \
        int av_ = __builtin_amdgcn_readlane(ecy, (jj)); \
        XV = *(const uint3*)(xs + (size_t)sv_ * 384 + c0); \
        TV = *(const uint3*)(tm + (size_t)av_ * 384 + c0); } while (0)
      int j = 0;
      if (m >= 4) {
        LDE(0, xA0, tA0); LDE(1, xA1, tA1); LDE(2, xA2, tA2); LDE(3, xA3, tA3);
        j = 4;
        for (; j + 8 <= m; j += 8) {
          LDE(j + 0, xB0, tB0); LDE(j + 1, xB1, tB1);
          LDE(j + 2, xB2, tB2); LDE(j + 3, xB3, tB3);
          proc(xA0, tA0); proc(xA1, tA1); proc(xA2, tA2); proc(xA3, tA3);
          LDE(j + 4, xA0, tA0); LDE(j + 5, xA1, tA1);
          LDE(j + 6, xA2, tA2); LDE(j + 7, xA3, tA3);
          proc(xB0, tB0); proc(xB1, tB1); proc(xB2, tB2); proc(xB3, tB3);
        }
        int r = m - j;
        if (r >= 4) {
          LDE(j + 0, xB0, tB0); LDE(j + 1, xB1, tB1);
          LDE(j + 2, xB2, tB2); LDE(j + 3, xB3, tB3);
          proc(xA0, tA0); proc(xA1, tA1); proc(xA2, tA2); proc(xA3, tA3);
          int r2 = r - 4;
          if (r2 > 0) LDE(j + 4, xA0, tA0);
          if (r2 > 1) LDE(j + 5, xA1, tA1);
          if (r2 > 2) LDE(j + 6, xA2, tA2);
          proc(xB0, tB0); proc(xB1, tB1); proc(xB2, tB2); proc(xB3, tB3);
          if (r2 > 0) proc(xA0, tA0);
          if (r2 > 1) proc(xA1, tA1);
          if (r2 > 2) proc(xA2, tA2);
        } else {
          if (r > 0) LDE(j + 0, xB0, tB0);
          if (r > 1) LDE(j + 1, xB1, tB1);
          if (r > 2) LDE(j + 2, xB2, tB2);
          proc(xA0, tA0); proc(xA1, tA1); proc(xA2, tA2); proc(xA3, tA3);
          if (r > 0) proc(xB0, tB0);
          if (r > 1) proc(xB1, tB1);
          if (r > 2) proc(xB2, tB2);
        }
      } else {
        if (m > 0) LDE(0, xA0, tA0);
        if (m > 1) LDE(1, xA1, tA1);
        if (m > 2) LDE(2, xA2, tA2);
        if (m > 0) proc(xA0, tA0);
        if (m > 1) proc(xA1, tA1);
        if (m > 2) proc(xA2, tA2);
      }
#undef LDE
    }
    float inv = inv_deg[n];
    bool empty = (o1 == o0);
    unsigned short* srow = sm + wv * SMS;
#pragma unroll
    for (int j = 0; j < 6; ++j) {
      int c = c0 + j;
      if (c < CH) {
        float me = s[j] * inv;
        float sd = sqrtf(fmaxf(q[j] * inv - me * me, 0.f) + 1e-5f);
        float mnv = empty ? 0.f : mn[j];
        float mxv = empty ? 0.f : mx[j];
        int t = c / 75, ch = c - t * 75;
        unsigned short* bb = srow + t * 320;
        bb[ch] = f2bfu(me);
        bb[75 + ch] = f2bfu(mnv);
        bb[150 + ch] = f2bfu(mxv);
        bb[225 + ch] = f2bfu(sd);
      }
    }
  }
  __syncthreads();
  // ---- phase 2: tower MFMA from LDS ----
  int m16 = lane & 15, quad = lane >> 4;
  if (wv < NT) {
    int tw = wv;
    const unsigned short* arow = sm + m16 * SMS + tw * 320 + quad * 8;
    const unsigned short* xrow = xh + (size_t)(rel0 + m16) * 160 + quad * 8;
    const unsigned short* bp = Bp + ((size_t)tw * 3 * 15 * 64) * 8 + lane * 8;
    v4f a0 = {0.f, 0.f, 0.f, 0.f}, a1 = a0, a2 = a0;
#pragma unroll
    for (int kb = 0; kb < 15; ++kb) {
      v8s av = *(const v8s*)((kb < 10) ? (arow + kb * 32) : (xrow + (kb - 10) * 32));
      const unsigned short* bb = bp + (size_t)kb * 512;
      v8s b0 = *(const v8s*)(bb);
      v8s b1 = *(const v8s*)(bb + 15 * 512);
      v8s b2 = *(const v8s*)(bb + 30 * 512);
      a0 = __builtin_amdgcn_mfma_f32_16x16x32_bf16(av, b0, a0, 0, 0, 0);
      a1 = __builtin_amdgcn_mfma_f32_16x16x32_bf16(av, b1, a1, 0, 0, 0);
      a2 = __builtin_amdgcn_mfma_f32_16x16x32_bf16(av, b2, a2, 0, 0, 0);
    }
    int f = m16;
    if (f < FO) {
      int relZ = quad * 4;
#pragma unroll
      for (int r = 0; r < 4; ++r) {
        int nd = rel0 + relZ + r;
        int ndc = (nd < NN) ? nd : (NN - 1);
        float zz = a0[r] + amp[ndc] * a1[r] + att[ndc] * a2[r];
        zs[(relZ + r) * 96 + tw * FO + f] = f2bfu(zz);
      }
    }
  }
  __syncthreads();
  // ---- phase 3: y cols [tw*16, tw*16+16) ----
  if (wv < NT) {
    int tw = wv;
    v4f acc2 = {0.f, 0.f, 0.f, 0.f};
#pragma unroll
    for (int kb = 0; kb < 3; ++kb) {
      v8s av = *(const v8s*)(zs + m16 * 96 + quad * 8 + kb * 32);
      v8s bl = *(const v8s*)(BlinL + ((size_t)(kb * 5 + tw) * 64 + lane) * 8);
      acc2 = __builtin_amdgcn_mfma_f32_16x16x32_bf16(av, bl, acc2, 0, 0, 0);
    }
    int fcol = tw * 16 + m16;
    if (fcol < FI) {
      float bcf = bcL[fcol];
      int nb = rel0 + quad * 4;
#pragma unroll
      for (int r = 0; r < 4; ++r) {
        int nd = nb + r;
        if (nd < NN) {
          float v = acc2[r] + bcf;
          yout[(size_t)nd * FI + fcol] = v;
          atomicAdd(&ysum[fcol], v);
          atomicAdd(&ysq[fcol], v * v);
        }
      }
    }
  }
  __syncthreads();
  if (tid < FI) {
    atomicAdd(&bnsum[tid], ysum[tid]);
    atomicAdd(&bnsum[FI + tid], ysq[tid]);
  }
}

// BN finalize+apply; dopool==0: zero pooled + build next layer's xh; dopool==1: pool.
__global__ __launch_bounds__(256) void k_bnfinapply(const float* __restrict__ y,
    const float* __restrict__ bnsum, const float* __restrict__ gamL,
    const float* __restrict__ betL, float* __restrict__ xo,
    const int* __restrict__ batch, float* __restrict__ pooled, int dopool,
    const int* __restrict__ deg, unsigned short* __restrict__ xh) {
  __shared__ float sc[150];
  int tid = threadIdx.x;
  if (tid < FI) {
    float mu = bnsum[tid] / (float)NN;
    float var = bnsum[FI + tid] / (float)NN - mu * mu;
    float scl = gamL[tid] * rsqrtf(var + 1e-5f);
    sc[tid] = scl;
    sc[FI + tid] = betL[tid] - mu * scl;
  }
  if (!dopool) {
    for (int i = blockIdx.x * 256 + tid; i < NG * FI; i += gridDim.x * 256)
      pooled[i] = 0.f;
  }
  __syncthreads();
  int stride = gridDim.x * 256;
  for (int i = blockIdx.x * 256 + tid; i < NN * FI; i += stride) {
    int n = i / FI, f = i - n * FI;
    float v = fmaxf(fmaf(y[i], sc[f], sc[FI + f]), 0.f);
    xo[i] = v;
    if (dopool) {
      atomicAdd(&pooled[batch[n] * FI + f], v);
    } else {
      // fused xh build for the next layer (pads 150..160 stay 0 from layer-0 pass)
      unsigned short hv = f2bfu(v);
      xh[(size_t)n * 160 + 75 + f] = hv;
      xh[(size_t)n * 160 + f] = (deg[n] > 0) ? hv : (unsigned short)0;
    }
  }
}

__global__ void k_head(const float* __restrict__ pooled, const float* __restrict__ W1,
                       const float* __restrict__ b1, const float* __restrict__ W2,
                       const float* __restrict__ b2, const float* __restrict__ W3,
                       const float* __restrict__ b3, float* __restrict__ out) {
  __shared__ float p[FI], h1[50], h2[25];
  int g = blockIdx.x, t = threadIdx.x;
  for (int i = t; i < FI; i += 64) p[i] = pooled[g * FI + i];
  __syncthreads();
  if (t < 50) {
    float a = b1[t];
    for (int j = 0; j < FI; ++j) a = fmaf(p[j], W1[j * 50 + t], a);
    h1[t] = fmaxf(a, 0.f);
  }
  __syncthreads();
  if (t < 25) {
    float a = b2[t];
    for (int j = 0; j < 50; ++j) a = fmaf(h1[j], W2[j * 25 + t], a);
    h2[t] = fmaxf(a, 0.f);
  }
  __syncthreads();
  if (t == 0) {
    float a = b3[0];
    for (int j = 0; j < 25; ++j) a = fmaf(h2[j], W3[j], a);
    out[g] = a;
  }
}

extern "C" void kernel_launch(void* const* d_in, const int* in_sizes, int n_in,
                              void* d_out, int out_size, void* d_ws, size_t ws_size,
                              hipStream_t stream) {
  const int* x_idx = (const int*)d_in[0];
  const int* eidx  = (const int*)d_in[1];
  const int* srcp  = eidx;
  const int* dstp  = eidx + NE;
  const int* eattr = (const int*)d_in[2];
  const int* batch = (const int*)d_in[3];
  const float* node_emb = (const float*)d_in[4];
  const float* edge_emb = (const float*)d_in[5];
  const float* W_edge = (const float*)d_in[6];
  const float* b_edge = (const float*)d_in[7];
  const float* W_pre  = (const float*)d_in[8];
  const float* b_pre  = (const float*)d_in[9];
  const float* W_post = (const float*)d_in[10];
  const float* b_post = (const float*)d_in[11];
  const float* W_lin  = (const float*)d_in[12];
  const float* b_lin  = (const float*)d_in[13];
  const float* gam = (const float*)d_in[14];
  const float* bet = (const float*)d_in[15];
  const float* W1 = (const float*)d_in[16];
  const float* b1 = (const float*)d_in[17];
  const float* W2 = (const float*)d_in[18];
  const float* b2 = (const float*)d_in[19];
  const float* W3 = (const float*)d_in[20];
  const float* b3 = (const float*)d_in[21];

  char* p = (char*)d_ws;
  auto alloc = [&](size_t b) -> char* {
    char* r = p;
    p += (b + 255) & ~(size_t)255;
    return r;
  };
  float* x_a   = (float*)alloc((size_t)NN * FI * 4);
  float* x_b   = (float*)alloc((size_t)NN * FI * 4);
  unsigned short* xs_bf = (unsigned short*)alloc((size_t)NN * 384 * 2);
  float* z     = (float*)alloc((size_t)NN * FI * 4);
  unsigned short* xh = (unsigned short*)alloc((size_t)(NN + 64) * 160 * 2);
  float* te    = (float*)alloc(2 * 100 * FI * 4);
  unsigned short* tm_bf = (unsigned short*)alloc((size_t)2 * 100 * 384 * 2);
  float* WAs   = (float*)alloc((size_t)2 * FI * CH * 4);
  float* V     = (float*)alloc((size_t)2 * NT * 3 * FI * 16 * 4);
  unsigned short* Bpk = (unsigned short*)alloc((size_t)230400 * 2);
  unsigned short* Bxs = (unsigned short*)alloc((size_t)73728 * 2);
  unsigned short* Blin = (unsigned short*)alloc((size_t)15360 * 2);
  float* bc    = (float*)alloc(2 * 76 * 4);
  float* ampv  = (float*)alloc((size_t)NN * 4);
  float* attv  = (float*)alloc((size_t)NN * 4);
  float* invv  = (float*)alloc((size_t)NN * 4);
  float* avglog = (float*)alloc(256);
  float* bnsumA = (float*)alloc(2 * FI * 4);
  float* bnsumB = (float*)alloc(2 * FI * 4);
  float* pooled = (float*)alloc((size_t)NG * FI * 4);
  int* deg = (int*)alloc((size_t)NN * 4);
  int* off = (int*)alloc((size_t)(NN + 1) * 4);
  int* cur = (int*)alloc((size_t)NN * 4);
  int2* csr = (int2*)alloc((size_t)NE * 8);

  hipMemsetAsync(deg, 0, (size_t)NN * 4, stream);

  k_mega1<<<7562, 256, 0, stream>>>(x_idx, node_emb, x_a, dstp, deg,
                                    edge_emb, W_edge, b_edge, te,
                                    W_pre, WAs, W_post, V,
                                    b_post, W_lin, b_lin, bc);
  k_mega2<<<389, 1024, 0, stream>>>(deg, off, cur, avglog,
                                    te, W_pre, b_pre, tm_bf, W_post, V, Bpk,
                                    WAs, Bxs, W_lin, Blin);
  k_mega3<<<1330, 256, 0, stream>>>(srcp, dstp, eattr, cur, csr,
                                    deg, avglog, ampv, attv, invv,
                                    bnsumA, bnsumB);

  for (int l = 0; l < 2; ++l) {
    const float* xin = (l == 0) ? x_a : x_b;
    float* xout = (l == 0) ? x_b : x_a;
    float* bns = (l == 0) ? bnsumA : bnsumB;
    // l==0: y=0 GEMM + y=1 xh build; l==1: y=0 only (xh fused into bnfinapply l=0)
    k_gemm_xs<<<dim3(625, (l == 0) ? 2 : 1), 256, 0, stream>>>(
        xin, Bxs + (size_t)l * 36864, xs_bf, deg, xh);
    k_aggpost<<<1250, 1024, 0, stream>>>(xs_bf, csr, off, invv,
                                         tm_bf + (size_t)l * 100 * 384, xh,
                                         Bpk + (size_t)l * 115200, ampv, attv,
                                         Blin + (size_t)l * 7680, bc + l * 76,
                                         z, bns);
    k_bnfinapply<<<1250, 256, 0, stream>>>(z, bns, gam + l * FI, bet + l * FI,
                                           xout, batch, pooled, (l == 1) ? 1 : 0,
                                           deg, xh);
  }

  k_head<<<NG, 64, 0, stream>>>(pooled, W1, b1, W2, b2, W3, b3, (float*)d_out);
}